// Round 1
// baseline (5292.480 us; speedup 1.0000x reference)
//
#include <hip/hip_runtime.h>
#include <hip/hip_bf16.h>
#include <math.h>

#define BT   16384   // B*T
#define CDIM 128
#define TSEQ 256
#define NBAT 64
#define NH   8
#define HD   16
#define NL   6
#define FFD  512
#define NV   3149

// ---------------------------------------------------------------- embed ----
__global__ __launch_bounds__(256) void embed_kernel(
    const int* __restrict__ tokens, const float* __restrict__ tok_emb,
    const float* __restrict__ pos_emb, float* __restrict__ x) {
  int i4 = blockIdx.x * 256 + threadIdx.x;         // float4 index
  if (i4 >= BT * CDIM / 4) return;
  int i  = i4 * 4;
  int c  = i & (CDIM - 1);
  int bt = i >> 7;
  int t  = bt & (TSEQ - 1);
  int tok = tokens[bt];
  float4 te = *(const float4*)(tok_emb + (size_t)tok * CDIM + c);
  float4 pe = *(const float4*)(pos_emb + (size_t)t * CDIM + c);
  float4 r;
  r.x = te.x + pe.x; r.y = te.y + pe.y; r.z = te.z + pe.z; r.w = te.w + pe.w;
  *(float4*)(x + i) = r;
}

// ------------------------------------------------------------- pack QKV ----
// Wq/Wk/Wv[l] are (H, C, D); pack into row-major (C=128) x (N=384):
// col j: j<128 -> q(h=j/16, d=j%16); 128..255 -> k; 256..383 -> v.
__global__ __launch_bounds__(256) void packqkv_kernel(
    const float* __restrict__ Wq, const float* __restrict__ Wk,
    const float* __restrict__ Wv, float* __restrict__ wpack) {
  int idx = blockIdx.x * 256 + threadIdx.x;
  if (idx >= NL * CDIM * 384) return;
  int j = idx % 384;
  int c = (idx / 384) % CDIM;
  int l = idx / (384 * CDIM);
  int sel = j >> 7;
  int jj  = j & 127;
  int h   = jj >> 4;
  int d   = jj & 15;
  const float* W = (sel == 0) ? Wq : (sel == 1) ? Wk : Wv;
  wpack[idx] = W[(((size_t)l * NH + h) * CDIM + c) * HD + d];
}

// ------------------------------------------------------------ layernorm ----
// one wave (64 lanes) per row of 128; float2 per lane
__global__ __launch_bounds__(256) void ln_kernel(
    const float* __restrict__ x, const float* __restrict__ g,
    const float* __restrict__ b, float* __restrict__ out) {
  int wid  = blockIdx.x * 4 + (threadIdx.x >> 6);
  int lane = threadIdx.x & 63;
  const float2 v = ((const float2*)(x + (size_t)wid * CDIM))[lane];
  float s = v.x + v.y;
  #pragma unroll
  for (int m = 1; m < 64; m <<= 1) s += __shfl_xor(s, m);
  float mu = s * (1.f / CDIM);
  float dx = v.x - mu, dy = v.y - mu;
  float s2 = dx * dx + dy * dy;
  #pragma unroll
  for (int m = 1; m < 64; m <<= 1) s2 += __shfl_xor(s2, m);
  float rstd = rsqrtf(s2 * (1.f / CDIM) + 1e-5f);
  float2 gg = ((const float2*)g)[lane];
  float2 bb = ((const float2*)b)[lane];
  float2 o;
  o.x = dx * rstd * gg.x + bb.x;
  o.y = dy * rstd * gg.y + bb.y;
  ((float2*)(out + (size_t)wid * CDIM))[lane] = o;
}

// ----------------------------------------------------------------- GEMM ----
// C[M,N] = epilogue(A[M,K] @ B[K,N]); row-major; BM=BN=64, BK=16, 4x4/thread
template<bool BIAS, bool RELU, bool RES>
__global__ __launch_bounds__(256) void gemm_f32(
    const float* __restrict__ A, const float* __restrict__ B,
    const float* __restrict__ bias, const float* __restrict__ res,
    float* __restrict__ C, int M, int N, int K) {
  constexpr int BM = 64, BN = 64, BK = 16;
  __shared__ __align__(16) float As[BK][BM + 4];
  __shared__ __align__(16) float Bs[BK][BN + 4];
  const int tid  = threadIdx.x;
  const int tcol = tid & 15;
  const int trow = tid >> 4;
  const int m0 = blockIdx.y * BM;
  const int n0 = blockIdx.x * BN;
  float acc[4][4] = {};
  for (int k0 = 0; k0 < K; k0 += BK) {
    #pragma unroll
    for (int j = 0; j < 4; j++) {              // A tile 64x16
      int i  = tid + j * 256;
      int m  = i >> 4;
      int kk = i & 15;
      As[kk][m] = A[(size_t)(m0 + m) * K + k0 + kk];
    }
    #pragma unroll
    for (int j = 0; j < 4; j++) {              // B tile 16x64
      int i   = tid + j * 256;
      int kk  = i >> 6;
      int n   = i & 63;
      int col = n0 + n;
      Bs[kk][n] = (col < N) ? B[(size_t)(k0 + kk) * N + col] : 0.f;
    }
    __syncthreads();
    #pragma unroll
    for (int kk = 0; kk < BK; kk++) {
      float4 a = *(const float4*)&As[kk][trow * 4];
      float4 b = *(const float4*)&Bs[kk][tcol * 4];
      float av[4] = {a.x, a.y, a.z, a.w};
      float bv[4] = {b.x, b.y, b.z, b.w};
      #pragma unroll
      for (int i = 0; i < 4; i++)
        #pragma unroll
        for (int j = 0; j < 4; j++)
          acc[i][j] += av[i] * bv[j];
    }
    __syncthreads();
  }
  #pragma unroll
  for (int i = 0; i < 4; i++) {
    int row = m0 + trow * 4 + i;
    #pragma unroll
    for (int j = 0; j < 4; j++) {
      int col = n0 + tcol * 4 + j;
      if (col < N) {
        float v = acc[i][j];
        if (BIAS) v += bias[col];
        if (RELU) v = fmaxf(v, 0.f);
        if (RES)  v += res[(size_t)row * N + col];
        C[(size_t)row * N + col] = v;
      }
    }
  }
}

// ------------------------------------------------------------ attention ----
// one wave per (b,h,t) query row; qkv layout: [bt][384] = q|k|v each h*16+d
__global__ __launch_bounds__(256) void attn_kernel(
    const float* __restrict__ qkv, float* __restrict__ out) {
  const float scale = 0.08838834764831843f;    // C^-0.5 (C=128, per reference!)
  int wave = blockIdx.x * 4 + (threadIdx.x >> 6);
  int lane = threadIdx.x & 63;
  int t = wave & (TSEQ - 1);
  int h = (wave >> 8) & (NH - 1);
  int b = wave >> 11;
  const float* qrow  = qkv + (size_t)(b * TSEQ + t) * 384 + h * HD;
  const float* kbase = qkv + (size_t)(b * TSEQ) * 384 + CDIM + h * HD;
  const float* vbase = qkv + (size_t)(b * TSEQ) * 384 + 2 * CDIM + h * HD;
  float qv[HD];
  #pragma unroll
  for (int d = 0; d < HD; d++) qv[d] = qrow[d];
  float sc[4];
  float mx = -3.4e38f;
  #pragma unroll
  for (int j = 0; j < 4; j++) {
    int s = lane + 64 * j;
    const float* kr = kbase + (size_t)s * 384;
    float dot = 0.f;
    #pragma unroll
    for (int d = 0; d < HD; d++) dot += qv[d] * kr[d];
    sc[j] = (s <= t) ? dot * scale : -3.4e38f;
    mx = fmaxf(mx, sc[j]);
  }
  #pragma unroll
  for (int m = 1; m < 64; m <<= 1) mx = fmaxf(mx, __shfl_xor(mx, m));
  float p[4];
  float sum = 0.f;
  #pragma unroll
  for (int j = 0; j < 4; j++) {
    p[j] = (sc[j] > -1e37f) ? __expf(sc[j] - mx) : 0.f;
    sum += p[j];
  }
  #pragma unroll
  for (int m = 1; m < 64; m <<= 1) sum += __shfl_xor(sum, m);
  float inv = 1.f / sum;
  float acc[HD] = {};
  #pragma unroll
  for (int j = 0; j < 4; j++) {
    int s = lane + 64 * j;
    const float* vr = vbase + (size_t)s * 384;
    #pragma unroll
    for (int d = 0; d < HD; d++) acc[d] += p[j] * vr[d];
  }
  #pragma unroll
  for (int d = 0; d < HD; d++) {
    #pragma unroll
    for (int m = 1; m < 64; m <<= 1) acc[d] += __shfl_xor(acc[d], m);
  }
  if (lane == 0) {
    float* o = out + (size_t)(b * TSEQ + t) * CDIM + h * HD;
    #pragma unroll
    for (int d = 0; d < HD; d++) o[d] = acc[d] * inv;
  }
}

// ----------------------------------------------------------------- host ----
extern "C" void kernel_launch(void* const* d_in, const int* in_sizes, int n_in,
                              void* d_out, int out_size, void* d_ws, size_t ws_size,
                              hipStream_t stream) {
  const int*   tokens  = (const int*)  d_in[0];
  const float* tok_emb = (const float*)d_in[1];
  const float* pos_emb = (const float*)d_in[2];
  const float* Wq      = (const float*)d_in[3];
  const float* Wk      = (const float*)d_in[4];
  const float* Wv      = (const float*)d_in[5];
  const float* Wproj   = (const float*)d_in[6];
  const float* bproj   = (const float*)d_in[7];
  const float* ln1_g   = (const float*)d_in[8];
  const float* ln1_b   = (const float*)d_in[9];
  const float* ln2_g   = (const float*)d_in[10];
  const float* ln2_b   = (const float*)d_in[11];
  const float* W1      = (const float*)d_in[12];
  const float* b1      = (const float*)d_in[13];
  const float* W2      = (const float*)d_in[14];
  const float* b2      = (const float*)d_in[15];
  const float* lnf_g   = (const float*)d_in[16];
  const float* lnf_b   = (const float*)d_in[17];
  const float* Wlm     = (const float*)d_in[18];
  const float* blm     = (const float*)d_in[19];
  float* out = (float*)d_out;

  float* ws    = (float*)d_ws;
  float* x     = ws;                       // 16384*128
  float* xn    = ws + 2097152;             // 16384*128
  float* qkv   = ws + 4194304;             // 16384*384
  float* att   = ws + 10485760;            // 16384*128
  float* hbuf  = ws + 12582912;            // 16384*512
  float* wpack = ws + 20971520;            // 6*128*384

  packqkv_kernel<<<(NL * CDIM * 384 + 255) / 256, 256, 0, stream>>>(Wq, Wk, Wv, wpack);
  embed_kernel<<<(BT * CDIM / 4 + 255) / 256, 256, 0, stream>>>(tokens, tok_emb, pos_emb, x);

  for (int l = 0; l < NL; l++) {
    ln_kernel<<<BT / 4, 256, 0, stream>>>(x, ln1_g + l * CDIM, ln1_b + l * CDIM, xn);
    gemm_f32<false, false, false><<<dim3(384 / 64, BT / 64), 256, 0, stream>>>(
        xn, wpack + (size_t)l * CDIM * 384, nullptr, nullptr, qkv, BT, 384, CDIM);
    attn_kernel<<<NBAT * NH * TSEQ / 4, 256, 0, stream>>>(qkv, att);
    gemm_f32<true, false, true><<<dim3(2, BT / 64), 256, 0, stream>>>(
        att, Wproj + (size_t)l * CDIM * CDIM, bproj + l * CDIM, x, x, BT, CDIM, CDIM);
    ln_kernel<<<BT / 4, 256, 0, stream>>>(x, ln2_g + l * CDIM, ln2_b + l * CDIM, xn);
    gemm_f32<true, true, false><<<dim3(FFD / 64, BT / 64), 256, 0, stream>>>(
        xn, W1 + (size_t)l * CDIM * FFD, b1 + l * FFD, nullptr, hbuf, BT, FFD, CDIM);
    gemm_f32<true, false, true><<<dim3(2, BT / 64), 256, 0, stream>>>(
        hbuf, W2 + (size_t)l * FFD * CDIM, b2 + l * CDIM, x, x, BT, CDIM, FFD);
  }
  ln_kernel<<<BT / 4, 256, 0, stream>>>(x, lnf_g, lnf_b, xn);
  gemm_f32<true, false, false><<<dim3((NV + 63) / 64, BT / 64), 256, 0, stream>>>(
      xn, Wlm, blm, nullptr, out, BT, NV, CDIM);
}

// Round 2
// 2032.783 us; speedup vs baseline: 2.6036x; 2.6036x over previous
//
#include <hip/hip_runtime.h>
#include <hip/hip_bf16.h>
#include <math.h>

#define BT   16384   // B*T
#define CDIM 128
#define TSEQ 256
#define NBAT 64
#define NH   8
#define HD   16
#define NL   6
#define FFD  512
#define NV   3149

// ---------------------------------------------------------------- embed ----
__global__ __launch_bounds__(256) void embed_kernel(
    const int* __restrict__ tokens, const float* __restrict__ tok_emb,
    const float* __restrict__ pos_emb, float* __restrict__ x) {
  int i4 = blockIdx.x * 256 + threadIdx.x;         // float4 index
  if (i4 >= BT * CDIM / 4) return;
  int i  = i4 * 4;
  int c  = i & (CDIM - 1);
  int bt = i >> 7;
  int t  = bt & (TSEQ - 1);
  int tok = tokens[bt];
  float4 te = *(const float4*)(tok_emb + (size_t)tok * CDIM + c);
  float4 pe = *(const float4*)(pos_emb + (size_t)t * CDIM + c);
  float4 r;
  r.x = te.x + pe.x; r.y = te.y + pe.y; r.z = te.z + pe.z; r.w = te.w + pe.w;
  *(float4*)(x + i) = r;
}

// ------------------------------------------------------------- pack QKV ----
__global__ __launch_bounds__(256) void packqkv_kernel(
    const float* __restrict__ Wq, const float* __restrict__ Wk,
    const float* __restrict__ Wv, float* __restrict__ wpack) {
  int idx = blockIdx.x * 256 + threadIdx.x;
  if (idx >= NL * CDIM * 384) return;
  int j = idx % 384;
  int c = (idx / 384) % CDIM;
  int l = idx / (384 * CDIM);
  int sel = j >> 7;
  int jj  = j & 127;
  int h   = jj >> 4;
  int d   = jj & 15;
  const float* W = (sel == 0) ? Wq : (sel == 1) ? Wk : Wv;
  wpack[idx] = W[(((size_t)l * NH + h) * CDIM + c) * HD + d];
}

// ------------------------------------------------------------ layernorm ----
__global__ __launch_bounds__(256) void ln_kernel(
    const float* __restrict__ x, const float* __restrict__ g,
    const float* __restrict__ b, float* __restrict__ out) {
  int wid  = blockIdx.x * 4 + (threadIdx.x >> 6);
  int lane = threadIdx.x & 63;
  const float2 v = ((const float2*)(x + (size_t)wid * CDIM))[lane];
  float s = v.x + v.y;
  #pragma unroll
  for (int m = 1; m < 64; m <<= 1) s += __shfl_xor(s, m);
  float mu = s * (1.f / CDIM);
  float dx = v.x - mu, dy = v.y - mu;
  float s2 = dx * dx + dy * dy;
  #pragma unroll
  for (int m = 1; m < 64; m <<= 1) s2 += __shfl_xor(s2, m);
  float rstd = rsqrtf(s2 * (1.f / CDIM) + 1e-5f);
  float2 gg = ((const float2*)g)[lane];
  float2 bb = ((const float2*)b)[lane];
  float2 o;
  o.x = dx * rstd * gg.x + bb.x;
  o.y = dy * rstd * gg.y + bb.y;
  ((float2*)(out + (size_t)wid * CDIM))[lane] = o;
}

// ----------------------------------------------------------------- GEMM ----
template<bool BIAS, bool RELU, bool RES>
__global__ __launch_bounds__(256) void gemm_f32(
    const float* __restrict__ A, const float* __restrict__ B,
    const float* __restrict__ bias, const float* __restrict__ res,
    float* __restrict__ C, int M, int N, int K) {
  constexpr int BM = 64, BN = 64, BK = 16;
  __shared__ __align__(16) float As[BK][BM + 4];
  __shared__ __align__(16) float Bs[BK][BN + 4];
  const int tid  = threadIdx.x;
  const int tcol = tid & 15;
  const int trow = tid >> 4;
  const int m0 = blockIdx.y * BM;
  const int n0 = blockIdx.x * BN;
  float acc[4][4] = {};
  for (int k0 = 0; k0 < K; k0 += BK) {
    #pragma unroll
    for (int j = 0; j < 4; j++) {              // A tile 64x16
      int i  = tid + j * 256;
      int m  = i >> 4;
      int kk = i & 15;
      As[kk][m] = A[(size_t)(m0 + m) * K + k0 + kk];
    }
    #pragma unroll
    for (int j = 0; j < 4; j++) {              // B tile 16x64
      int i   = tid + j * 256;
      int kk  = i >> 6;
      int n   = i & 63;
      int col = n0 + n;
      Bs[kk][n] = (col < N) ? B[(size_t)(k0 + kk) * N + col] : 0.f;
    }
    __syncthreads();
    #pragma unroll
    for (int kk = 0; kk < BK; kk++) {
      float4 a = *(const float4*)&As[kk][trow * 4];
      float4 b = *(const float4*)&Bs[kk][tcol * 4];
      float av[4] = {a.x, a.y, a.z, a.w};
      float bv[4] = {b.x, b.y, b.z, b.w};
      #pragma unroll
      for (int i = 0; i < 4; i++)
        #pragma unroll
        for (int j = 0; j < 4; j++)
          acc[i][j] += av[i] * bv[j];
    }
    __syncthreads();
  }
  #pragma unroll
  for (int i = 0; i < 4; i++) {
    int row = m0 + trow * 4 + i;
    #pragma unroll
    for (int j = 0; j < 4; j++) {
      int col = n0 + tcol * 4 + j;
      if (col < N) {
        float v = acc[i][j];
        if (BIAS) v += bias[col];
        if (RELU) v = fmaxf(v, 0.f);
        if (RES)  v += res[(size_t)row * N + col];
        C[(size_t)row * N + col] = v;
      }
    }
  }
}

// ------------------------------------------------------------ attention ----
// one workgroup per (b,h). K/V/Q for the head staged in LDS; each of 4 waves
// handles 64 interleaved query rows (t = qi*4 + wave).
__global__ __launch_bounds__(256) void attn_kernel(
    const float* __restrict__ qkv, float* __restrict__ out) {
  const float scale = 0.08838834764831843f;    // C^-0.5 (C=128, per reference!)
  __shared__ float Ks[TSEQ][HD + 1];           // pad 17: 2-way bank alias (free)
  __shared__ float Vs[TSEQ][HD + 1];
  __shared__ float Qs[TSEQ][HD];
  const int bh = blockIdx.x;
  const int h = bh & (NH - 1);
  const int b = bh >> 3;
  const int tid = threadIdx.x;

  // stage: 4 passes; threads (r = tid>>2, c4 = (tid&3)*4) -> 64B-coalesced groups
  #pragma unroll
  for (int pass = 0; pass < 4; pass++) {
    int r  = (tid >> 2) + pass * 64;
    int c4 = (tid & 3) * 4;
    const float* base = qkv + (size_t)(b * TSEQ + r) * 384 + h * HD + c4;
    float4 qq = *(const float4*)(base);
    float4 kk = *(const float4*)(base + CDIM);
    float4 vv = *(const float4*)(base + 2 * CDIM);
    *(float4*)&Qs[r][c4] = qq;
    Ks[r][c4+0] = kk.x; Ks[r][c4+1] = kk.y; Ks[r][c4+2] = kk.z; Ks[r][c4+3] = kk.w;
    Vs[r][c4+0] = vv.x; Vs[r][c4+1] = vv.y; Vs[r][c4+2] = vv.z; Vs[r][c4+3] = vv.w;
  }
  __syncthreads();

  const int wv   = tid >> 6;
  const int lane = tid & 63;

  for (int qi = 0; qi < 64; qi++) {
    const int t = qi * 4 + wv;            // wave-uniform
    const int nch = t >> 6;               // chunks j <= nch are (partially) live
    float qv[HD];
    *(float4*)&qv[0]  = *(const float4*)&Qs[t][0];
    *(float4*)&qv[4]  = *(const float4*)&Qs[t][4];
    *(float4*)&qv[8]  = *(const float4*)&Qs[t][8];
    *(float4*)&qv[12] = *(const float4*)&Qs[t][12];

    float sc[4];
    float mx = -3.4e38f;
    #pragma unroll
    for (int j = 0; j < 4; j++) {
      sc[j] = -3.4e38f;
      if (j <= nch) {                     // wave-uniform guard
        int s = lane + (j << 6);
        float dot = 0.f;
        #pragma unroll
        for (int d = 0; d < HD; d++) dot += qv[d] * Ks[s][d];
        if (s <= t) sc[j] = dot * scale;
        mx = fmaxf(mx, sc[j]);
      }
    }
    #pragma unroll
    for (int m = 1; m < 64; m <<= 1) mx = fmaxf(mx, __shfl_xor(mx, m));

    float p[4];
    float sum = 0.f;
    #pragma unroll
    for (int j = 0; j < 4; j++) {
      p[j] = 0.f;
      if (j <= nch) {
        if (sc[j] > -1e37f) p[j] = __expf(sc[j] - mx);
        sum += p[j];
      }
    }
    #pragma unroll
    for (int m = 1; m < 64; m <<= 1) sum += __shfl_xor(sum, m);
    const float inv = 1.f / sum;

    float acc[HD];
    #pragma unroll
    for (int d = 0; d < HD; d++) acc[d] = 0.f;
    #pragma unroll
    for (int j = 0; j < 4; j++) {
      if (j <= nch) {
        int s = lane + (j << 6);
        float pj = p[j];
        #pragma unroll
        for (int d = 0; d < HD; d++) acc[d] += pj * Vs[s][d];
      }
    }

    // log-tree reduce: 16 values across 64 lanes (keep-half-per-step)
    float v8[8];
    { const bool hi = lane & 1;
      #pragma unroll
      for (int i = 0; i < 8; i++) {
        float snd = hi ? acc[i] : acc[i + 8];
        float rcv = __shfl_xor(snd, 1);
        v8[i] = (hi ? acc[i + 8] : acc[i]) + rcv;
      } }
    float v4[4];
    { const bool hi = (lane >> 1) & 1;
      #pragma unroll
      for (int i = 0; i < 4; i++) {
        float snd = hi ? v8[i] : v8[i + 4];
        float rcv = __shfl_xor(snd, 2);
        v4[i] = (hi ? v8[i + 4] : v8[i]) + rcv;
      } }
    float v2[2];
    { const bool hi = (lane >> 2) & 1;
      #pragma unroll
      for (int i = 0; i < 2; i++) {
        float snd = hi ? v2[i] - v2[i] + v4[i] : v4[i + 2];  // placeholder avoided below
        snd = hi ? v4[i] : v4[i + 2];
        float rcv = __shfl_xor(snd, 4);
        v2[i] = (hi ? v4[i + 2] : v4[i]) + rcv;
      } }
    float v1;
    { const bool hi = (lane >> 3) & 1;
      float snd = hi ? v2[0] : v2[1];
      float rcv = __shfl_xor(snd, 8);
      v1 = (hi ? v2[1] : v2[0]) + rcv; }
    v1 += __shfl_xor(v1, 16);
    v1 += __shfl_xor(v1, 32);

    if (lane < 16) {
      int d = ((lane & 1) << 3) | (((lane >> 1) & 1) << 2) |
              (((lane >> 2) & 1) << 1) | ((lane >> 3) & 1);
      out[((size_t)(b * TSEQ + t)) * CDIM + h * HD + d] = v1 * inv;
    }
  }
}

// ----------------------------------------------------------------- host ----
extern "C" void kernel_launch(void* const* d_in, const int* in_sizes, int n_in,
                              void* d_out, int out_size, void* d_ws, size_t ws_size,
                              hipStream_t stream) {
  const int*   tokens  = (const int*)  d_in[0];
  const float* tok_emb = (const float*)d_in[1];
  const float* pos_emb = (const float*)d_in[2];
  const float* Wq      = (const float*)d_in[3];
  const float* Wk      = (const float*)d_in[4];
  const float* Wv      = (const float*)d_in[5];
  const float* Wproj   = (const float*)d_in[6];
  const float* bproj   = (const float*)d_in[7];
  const float* ln1_g   = (const float*)d_in[8];
  const float* ln1_b   = (const float*)d_in[9];
  const float* ln2_g   = (const float*)d_in[10];
  const float* ln2_b   = (const float*)d_in[11];
  const float* W1      = (const float*)d_in[12];
  const float* b1      = (const float*)d_in[13];
  const float* W2      = (const float*)d_in[14];
  const float* b2      = (const float*)d_in[15];
  const float* lnf_g   = (const float*)d_in[16];
  const float* lnf_b   = (const float*)d_in[17];
  const float* Wlm     = (const float*)d_in[18];
  const float* blm     = (const float*)d_in[19];
  float* out = (float*)d_out;

  float* ws    = (float*)d_ws;
  float* x     = ws;                       // 16384*128
  float* xn    = ws + 2097152;             // 16384*128
  float* qkv   = ws + 4194304;             // 16384*384
  float* att   = ws + 10485760;            // 16384*128
  float* hbuf  = ws + 12582912;            // 16384*512
  float* wpack = ws + 20971520;            // 6*128*384

  packqkv_kernel<<<(NL * CDIM * 384 + 255) / 256, 256, 0, stream>>>(Wq, Wk, Wv, wpack);
  embed_kernel<<<(BT * CDIM / 4 + 255) / 256, 256, 0, stream>>>(tokens, tok_emb, pos_emb, x);

  for (int l = 0; l < NL; l++) {
    ln_kernel<<<BT / 4, 256, 0, stream>>>(x, ln1_g + l * CDIM, ln1_b + l * CDIM, xn);
    gemm_f32<false, false, false><<<dim3(384 / 64, BT / 64), 256, 0, stream>>>(
        xn, wpack + (size_t)l * CDIM * 384, nullptr, nullptr, qkv, BT, 384, CDIM);
    attn_kernel<<<NBAT * NH, 256, 0, stream>>>(qkv, att);
    gemm_f32<true, false, true><<<dim3(2, BT / 64), 256, 0, stream>>>(
        att, Wproj + (size_t)l * CDIM * CDIM, bproj + l * CDIM, x, x, BT, CDIM, CDIM);
    ln_kernel<<<BT / 4, 256, 0, stream>>>(x, ln2_g + l * CDIM, ln2_b + l * CDIM, xn);
    gemm_f32<true, true, false><<<dim3(FFD / 64, BT / 64), 256, 0, stream>>>(
        xn, W1 + (size_t)l * CDIM * FFD, b1 + l * FFD, nullptr, hbuf, BT, FFD, CDIM);
    gemm_f32<true, false, true><<<dim3(2, BT / 64), 256, 0, stream>>>(
        hbuf, W2 + (size_t)l * FFD * CDIM, b2 + l * CDIM, x, x, BT, CDIM, FFD);
  }
  ln_kernel<<<BT / 4, 256, 0, stream>>>(x, lnf_g, lnf_b, xn);
  gemm_f32<true, false, false><<<dim3((NV + 63) / 64, BT / 64), 256, 0, stream>>>(
      xn, Wlm, blm, nullptr, out, BT, NV, CDIM);
}

// Round 3
// 1286.589 us; speedup vs baseline: 4.1136x; 1.5800x over previous
//
#include <hip/hip_runtime.h>
#include <hip/hip_bf16.h>
#include <math.h>

#define BT   16384   // B*T
#define CDIM 128
#define TSEQ 256
#define NBAT 64
#define NH   8
#define HD   16
#define NL   6
#define FFD  512
#define NV   3149

typedef __bf16 bfv8 __attribute__((ext_vector_type(8)));
typedef float  fv4  __attribute__((ext_vector_type(4)));
typedef unsigned short u16;
typedef unsigned int   u32;
typedef u16 u16v8 __attribute__((ext_vector_type(8)));

__device__ __forceinline__ u16 f2b(float f) {
  u32 u = __builtin_bit_cast(u32, f);
  u += 0x7FFFu + ((u >> 16) & 1u);        // round-to-nearest-even
  return (u16)(u >> 16);
}
__device__ __forceinline__ float b2f(u16 h) {
  return __builtin_bit_cast(float, (u32)h << 16);
}

// ---------------------------------------------------------------- embed ----
__global__ __launch_bounds__(256) void embed_kernel(
    const int* __restrict__ tokens, const float* __restrict__ tok_emb,
    const float* __restrict__ pos_emb, float* __restrict__ x) {
  int i4 = blockIdx.x * 256 + threadIdx.x;
  if (i4 >= BT * CDIM / 4) return;
  int i  = i4 * 4;
  int c  = i & (CDIM - 1);
  int bt = i >> 7;
  int t  = bt & (TSEQ - 1);
  int tok = tokens[bt];
  float4 te = *(const float4*)(tok_emb + (size_t)tok * CDIM + c);
  float4 pe = *(const float4*)(pos_emb + (size_t)t * CDIM + c);
  float4 r;
  r.x = te.x + pe.x; r.y = te.y + pe.y; r.z = te.z + pe.z; r.w = te.w + pe.w;
  *(float4*)(x + i) = r;
}

// ------------------------------------------------- weight pack (bf16 B^T) --
// qkv pack: dst[l][j][c], j<128 q(h=j/16,d=j%16), 128..255 k, 256..383 v
__global__ __launch_bounds__(256) void packqkv_bf16(
    const float* __restrict__ Wq, const float* __restrict__ Wk,
    const float* __restrict__ Wv, u16* __restrict__ dst) {
  int idx = blockIdx.x * 256 + threadIdx.x;
  if (idx >= NL * 384 * CDIM) return;
  int c = idx & 127;
  int j = (idx >> 7) % 384;
  int l = idx / (384 * CDIM);
  int sel = j >> 7;
  int jj  = j & 127;
  int h   = jj >> 4;
  int d   = jj & 15;
  const float* W = (sel == 0) ? Wq : (sel == 1) ? Wk : Wv;
  dst[idx] = f2b(W[(((size_t)l * NH + h) * CDIM + c) * HD + d]);
}

// src[l][r][c] -> dst[l][c][r] (bf16), r fastest in idx => coalesced writes
__global__ __launch_bounds__(256) void transpose_cast(
    const float* __restrict__ src, u16* __restrict__ dst, int R, int C, int L) {
  int idx = blockIdx.x * 256 + threadIdx.x;
  if (idx >= L * R * C) return;
  int r = idx % R;
  int c = (idx / R) % C;
  int l = idx / (R * C);
  dst[idx] = f2b(src[((size_t)l * R + r) * C + c]);
}

// ------------------------------------------------------------ layernorm ----
// one wave per row of 128; f32 in, bf16 out
__global__ __launch_bounds__(256) void ln_kernel(
    const float* __restrict__ x, const float* __restrict__ g,
    const float* __restrict__ b, u16* __restrict__ out) {
  int wid  = blockIdx.x * 4 + (threadIdx.x >> 6);
  int lane = threadIdx.x & 63;
  const float2 v = ((const float2*)(x + (size_t)wid * CDIM))[lane];
  float s = v.x + v.y;
  #pragma unroll
  for (int m = 1; m < 64; m <<= 1) s += __shfl_xor(s, m);
  float mu = s * (1.f / CDIM);
  float dx = v.x - mu, dy = v.y - mu;
  float s2 = dx * dx + dy * dy;
  #pragma unroll
  for (int m = 1; m < 64; m <<= 1) s2 += __shfl_xor(s2, m);
  float rstd = rsqrtf(s2 * (1.f / CDIM) + 1e-5f);
  float2 gg = ((const float2*)g)[lane];
  float2 bb = ((const float2*)b)[lane];
  u32 pack = (u32)f2b(dx * rstd * gg.x + bb.x) |
             ((u32)f2b(dy * rstd * gg.y + bb.y) << 16);
  ((u32*)(out + (size_t)wid * CDIM))[lane] = pack;
}

// ------------------------------------------------------------ MFMA GEMM ----
// C[M,N] = epi(A[M,K] @ Bt[N,K]^T); A,Bt bf16; BM=128, BK=32, 4 waves (2x2)
// OMODE: 0 = bf16 out, 1 = f32 out, 2 = f32 += (residual in-place)
template<int OMODE, bool BIAS, bool RELU, int BN>
__global__ __launch_bounds__(256) void gemm_mfma(
    const u16* __restrict__ A, const u16* __restrict__ Btp,
    const float* __restrict__ bias, void* __restrict__ Cout,
    int M, int N, int K) {
  constexpr int BM = 128, BK = 32, PAD = 40;
  constexpr int NF = BN / 32;              // n-frags per wave
  __shared__ u16 As[BM][PAD];
  __shared__ u16 Bs[BN][PAD];
  const int tid  = threadIdx.x;
  const int lane = tid & 63;
  const int wv   = tid >> 6;
  const int wm   = wv & 1;
  const int wn   = wv >> 1;
  const int m0 = blockIdx.y * BM;
  const int n0 = blockIdx.x * BN;
  const int srow = tid >> 2;
  const int sk8  = (tid & 3) * 8;
  const int fr = lane & 15;                // frag row(A)/col(B)
  const int fk = (lane >> 4) * 8;          // frag k offset

  fv4 acc[4][NF];
  #pragma unroll
  for (int i = 0; i < 4; i++)
    #pragma unroll
    for (int j = 0; j < NF; j++) acc[i][j] = (fv4){0.f, 0.f, 0.f, 0.f};

  for (int k0 = 0; k0 < K; k0 += BK) {
    #pragma unroll
    for (int p = 0; p < 2; p++) {
      int r = srow + p * 64;
      *(uint4*)&As[r][sk8] = *(const uint4*)(A + (size_t)(m0 + r) * K + k0 + sk8);
    }
    #pragma unroll
    for (int p = 0; p < BN / 64; p++) {
      int r = srow + p * 64;
      int n = n0 + r;
      uint4 v = make_uint4(0u, 0u, 0u, 0u);
      if (n < N) v = *(const uint4*)(Btp + (size_t)n * K + k0 + sk8);
      *(uint4*)&Bs[r][sk8] = v;
    }
    __syncthreads();
    bfv8 a[4], b[NF];
    #pragma unroll
    for (int i = 0; i < 4; i++)
      a[i] = *(const bfv8*)&As[wm * 64 + i * 16 + fr][fk];
    #pragma unroll
    for (int j = 0; j < NF; j++)
      b[j] = *(const bfv8*)&Bs[wn * (BN / 2) + j * 16 + fr][fk];
    #pragma unroll
    for (int i = 0; i < 4; i++)
      #pragma unroll
      for (int j = 0; j < NF; j++)
        acc[i][j] = __builtin_amdgcn_mfma_f32_16x16x32_bf16(a[i], b[j], acc[i][j], 0, 0, 0);
    __syncthreads();
  }

  const int row0 = m0 + wm * 64;
  const int col0 = n0 + wn * (BN / 2);
  const int lr   = (lane >> 4) * 4;
  #pragma unroll
  for (int j = 0; j < NF; j++) {
    int col = col0 + j * 16 + fr;
    if (col >= N) continue;
    float bz = BIAS ? bias[col] : 0.f;
    #pragma unroll
    for (int i = 0; i < 4; i++) {
      #pragma unroll
      for (int q = 0; q < 4; q++) {
        int row = row0 + i * 16 + lr + q;
        float v = acc[i][j][q] + bz;
        if (RELU) v = fmaxf(v, 0.f);
        if (OMODE == 0)      ((u16*)Cout)[(size_t)row * N + col] = f2b(v);
        else if (OMODE == 1) ((float*)Cout)[(size_t)row * N + col] = v;
        else                 ((float*)Cout)[(size_t)row * N + col] += v;
      }
    }
  }
}

// ------------------------------------------------------------ attention ----
// one workgroup per (b,h); bf16 qkv in, bf16 att out; K/V rows 16B-aligned
__device__ __forceinline__ float dot16(const float4 q[4], const float* kr) {
  const float4* k4 = (const float4*)kr;
  float4 a = k4[0], b = k4[1], c = k4[2], d = k4[3];
  return q[0].x*a.x + q[0].y*a.y + q[0].z*a.z + q[0].w*a.w
       + q[1].x*b.x + q[1].y*b.y + q[1].z*b.z + q[1].w*b.w
       + q[2].x*c.x + q[2].y*c.y + q[2].z*c.z + q[2].w*c.w
       + q[3].x*d.x + q[3].y*d.y + q[3].z*d.z + q[3].w*d.w;
}

__global__ __launch_bounds__(256) void attn_kernel(
    const u16* __restrict__ qkv, u16* __restrict__ out) {
  const float scale = 0.08838834764831843f;   // C^-0.5 (C=128, per reference!)
  __shared__ float Ks[TSEQ][20];              // 80B rows: aligned + uniform banks
  __shared__ float Vs[TSEQ][20];
  __shared__ float Qs[TSEQ][16];
  const int bh = blockIdx.x;
  const int h = bh & (NH - 1);
  const int b = bh >> 3;
  const int tid = threadIdx.x;

  #pragma unroll
  for (int p = 0; p < 2; p++) {
    int idx = tid + p * 256;
    int r  = idx >> 1;
    int c8 = (idx & 1) * 8;
    const u16* base = qkv + (size_t)(b * TSEQ + r) * 384 + h * HD + c8;
    u16v8 q = *(const u16v8*)(base);
    u16v8 k = *(const u16v8*)(base + CDIM);
    u16v8 v = *(const u16v8*)(base + 2 * CDIM);
    #pragma unroll
    for (int i = 0; i < 8; i++) {
      Qs[r][c8 + i] = b2f(q[i]);
      Ks[r][c8 + i] = b2f(k[i]);
      Vs[r][c8 + i] = b2f(v[i]);
    }
  }
  __syncthreads();

  const int wv   = tid >> 6;
  const int lane = tid & 63;

  for (int qi = 0; qi < 64; qi++) {
    const int t = qi * 4 + wv;            // wave-uniform
    const int nch = t >> 6;
    float4 qv4[4];
    qv4[0] = *(const float4*)&Qs[t][0];
    qv4[1] = *(const float4*)&Qs[t][4];
    qv4[2] = *(const float4*)&Qs[t][8];
    qv4[3] = *(const float4*)&Qs[t][12];

    float sc[4];
    float mx = -3.4e38f;
    #pragma unroll
    for (int j = 0; j < 4; j++) {
      sc[j] = -3.4e38f;
      if (j <= nch) {
        int s = lane + (j << 6);
        float dot = dot16(qv4, &Ks[s][0]);
        if (s <= t) sc[j] = dot * scale;
        mx = fmaxf(mx, sc[j]);
      }
    }
    #pragma unroll
    for (int m = 1; m < 64; m <<= 1) mx = fmaxf(mx, __shfl_xor(mx, m));

    float p[4];
    float sum = 0.f;
    #pragma unroll
    for (int j = 0; j < 4; j++) {
      p[j] = 0.f;
      if (j <= nch) {
        if (sc[j] > -1e37f) p[j] = __expf(sc[j] - mx);
        sum += p[j];
      }
    }
    #pragma unroll
    for (int m = 1; m < 64; m <<= 1) sum += __shfl_xor(sum, m);
    const float inv = 1.f / sum;

    float4 a4[4];
    #pragma unroll
    for (int c = 0; c < 4; c++) a4[c] = make_float4(0.f, 0.f, 0.f, 0.f);
    #pragma unroll
    for (int j = 0; j < 4; j++) {
      if (j <= nch) {
        int s = lane + (j << 6);
        float pj = p[j];
        const float4* v4 = (const float4*)&Vs[s][0];
        #pragma unroll
        for (int c = 0; c < 4; c++) {
          float4 vv = v4[c];
          a4[c].x += pj * vv.x; a4[c].y += pj * vv.y;
          a4[c].z += pj * vv.z; a4[c].w += pj * vv.w;
        }
      }
    }
    float acc[HD];
    #pragma unroll
    for (int c = 0; c < 4; c++) {
      acc[c*4+0] = a4[c].x; acc[c*4+1] = a4[c].y;
      acc[c*4+2] = a4[c].z; acc[c*4+3] = a4[c].w;
    }

    // log-tree reduce: 16 values across 64 lanes
    float v8[8];
    { const bool hi = lane & 1;
      #pragma unroll
      for (int i = 0; i < 8; i++) {
        float snd = hi ? acc[i] : acc[i + 8];
        float rcv = __shfl_xor(snd, 1);
        v8[i] = (hi ? acc[i + 8] : acc[i]) + rcv;
      } }
    float v4r[4];
    { const bool hi = (lane >> 1) & 1;
      #pragma unroll
      for (int i = 0; i < 4; i++) {
        float snd = hi ? v8[i] : v8[i + 4];
        float rcv = __shfl_xor(snd, 2);
        v4r[i] = (hi ? v8[i + 4] : v8[i]) + rcv;
      } }
    float v2r[2];
    { const bool hi = (lane >> 2) & 1;
      #pragma unroll
      for (int i = 0; i < 2; i++) {
        float snd = hi ? v4r[i] : v4r[i + 2];
        float rcv = __shfl_xor(snd, 4);
        v2r[i] = (hi ? v4r[i + 2] : v4r[i]) + rcv;
      } }
    float v1;
    { const bool hi = (lane >> 3) & 1;
      float snd = hi ? v2r[0] : v2r[1];
      float rcv = __shfl_xor(snd, 8);
      v1 = (hi ? v2r[1] : v2r[0]) + rcv; }
    v1 += __shfl_xor(v1, 16);
    v1 += __shfl_xor(v1, 32);

    if (lane < 16) {
      int d = ((lane & 1) << 3) | (((lane >> 1) & 1) << 2) |
              (((lane >> 2) & 1) << 1) | ((lane >> 3) & 1);
      out[((size_t)(b * TSEQ + t)) * CDIM + h * HD + d] = f2b(v1 * inv);
    }
  }
}

// ----------------------------------------------------------------- host ----
extern "C" void kernel_launch(void* const* d_in, const int* in_sizes, int n_in,
                              void* d_out, int out_size, void* d_ws, size_t ws_size,
                              hipStream_t stream) {
  const int*   tokens  = (const int*)  d_in[0];
  const float* tok_emb = (const float*)d_in[1];
  const float* pos_emb = (const float*)d_in[2];
  const float* Wq      = (const float*)d_in[3];
  const float* Wk      = (const float*)d_in[4];
  const float* Wv      = (const float*)d_in[5];
  const float* Wproj   = (const float*)d_in[6];
  const float* bproj   = (const float*)d_in[7];
  const float* ln1_g   = (const float*)d_in[8];
  const float* ln1_b   = (const float*)d_in[9];
  const float* ln2_g   = (const float*)d_in[10];
  const float* ln2_b   = (const float*)d_in[11];
  const float* W1      = (const float*)d_in[12];
  const float* b1      = (const float*)d_in[13];
  const float* W2      = (const float*)d_in[14];
  const float* b2      = (const float*)d_in[15];
  const float* lnf_g   = (const float*)d_in[16];
  const float* lnf_b   = (const float*)d_in[17];
  const float* Wlm     = (const float*)d_in[18];
  const float* blm     = (const float*)d_in[19];
  float* out = (float*)d_out;

  char* W = (char*)d_ws;
  float* x    = (float*)(W);                   // 16384*128 f32      (8 MB)
  u16*   xn   = (u16*)  (W + 8388608);         // 16384*128 bf16     (4 MB)
  u16*   qkvb = (u16*)  (W + 12582912);        // 16384*384 bf16     (12 MB)
  u16*   att  = (u16*)  (W + 25165824);        // 16384*128 bf16     (4 MB)
  u16*   hbuf = (u16*)  (W + 29360128);        // 16384*512 bf16     (16 MB)
  u16*   wqkv = (u16*)  (W + 46137344);        // 6*384*128
  u16*   wpj  = (u16*)  (W + 46727168);        // 6*128*128
  u16*   w1t  = (u16*)  (W + 46923776);        // 6*512*128
  u16*   w2t  = (u16*)  (W + 47710208);        // 6*128*512
  u16*   wlmt = (u16*)  (W + 48496640);        // 3149*128

  packqkv_bf16<<<(NL * 384 * CDIM + 255) / 256, 256, 0, stream>>>(Wq, Wk, Wv, wqkv);
  transpose_cast<<<(NL * CDIM * CDIM + 255) / 256, 256, 0, stream>>>(Wproj, wpj, CDIM, CDIM, NL);
  transpose_cast<<<(NL * CDIM * FFD + 255) / 256, 256, 0, stream>>>(W1, w1t, CDIM, FFD, NL);
  transpose_cast<<<(NL * FFD * CDIM + 255) / 256, 256, 0, stream>>>(W2, w2t, FFD, CDIM, NL);
  transpose_cast<<<(CDIM * NV + 255) / 256, 256, 0, stream>>>(Wlm, wlmt, CDIM, NV, 1);
  embed_kernel<<<(BT * CDIM / 4 + 255) / 256, 256, 0, stream>>>(tokens, tok_emb, pos_emb, x);

  for (int l = 0; l < NL; l++) {
    ln_kernel<<<BT / 4, 256, 0, stream>>>(x, ln1_g + l * CDIM, ln1_b + l * CDIM, xn);
    gemm_mfma<0, false, false, 128><<<dim3(3, BT / 128), 256, 0, stream>>>(
        xn, wqkv + (size_t)l * 384 * CDIM, nullptr, qkvb, BT, 384, CDIM);
    attn_kernel<<<NBAT * NH, 256, 0, stream>>>(qkvb, att);
    gemm_mfma<2, true, false, 64><<<dim3(2, BT / 128), 256, 0, stream>>>(
        att, wpj + (size_t)l * CDIM * CDIM, bproj + l * CDIM, x, BT, CDIM, CDIM);
    ln_kernel<<<BT / 4, 256, 0, stream>>>(x, ln2_g + l * CDIM, ln2_b + l * CDIM, xn);
    gemm_mfma<0, true, true, 128><<<dim3(4, BT / 128), 256, 0, stream>>>(
        xn, w1t + (size_t)l * FFD * CDIM, b1 + l * FFD, hbuf, BT, FFD, CDIM);
    gemm_mfma<2, true, false, 64><<<dim3(2, BT / 128), 256, 0, stream>>>(
        hbuf, w2t + (size_t)l * CDIM * FFD, b2 + l * CDIM, x, BT, CDIM, FFD);
  }
  ln_kernel<<<BT / 4, 256, 0, stream>>>(x, lnf_g, lnf_b, xn);
  gemm_mfma<1, true, false, 128><<<dim3((NV + 127) / 128, BT / 128), 256, 0, stream>>>(
      xn, wlmt, blm, out, BT, NV, CDIM);
}

// Round 4
// 856.864 us; speedup vs baseline: 6.1766x; 1.5015x over previous
//
#include <hip/hip_runtime.h>
#include <hip/hip_bf16.h>
#include <math.h>

#define BT   16384   // B*T
#define CDIM 128
#define TSEQ 256
#define NBAT 64
#define NH   8
#define HD   16
#define NL   6
#define FFD  512
#define NV   3149

typedef __bf16 bfv8 __attribute__((ext_vector_type(8)));
typedef float  fv4  __attribute__((ext_vector_type(4)));
typedef unsigned short u16;
typedef unsigned int   u32;
typedef u16 u16v8 __attribute__((ext_vector_type(8)));

__device__ __forceinline__ u16 f2b(float f) {
  u32 u = __builtin_bit_cast(u32, f);
  u += 0x7FFFu + ((u >> 16) & 1u);        // round-to-nearest-even
  return (u16)(u >> 16);
}
__device__ __forceinline__ float b2f(u16 h) {
  return __builtin_bit_cast(float, (u32)h << 16);
}
__device__ __forceinline__ u32 cvtpk(float lo, float hi) {
  u32 r;
  asm("v_cvt_pk_bf16_f32 %0, %1, %2" : "=v"(r) : "v"(lo), "v"(hi));
  return r;
}

// ---------------------------------------------------------------- embed ----
__global__ __launch_bounds__(256) void embed_kernel(
    const int* __restrict__ tokens, const float* __restrict__ tok_emb,
    const float* __restrict__ pos_emb, float* __restrict__ x) {
  int i4 = blockIdx.x * 256 + threadIdx.x;
  if (i4 >= BT * CDIM / 4) return;
  int i  = i4 * 4;
  int c  = i & (CDIM - 1);
  int bt = i >> 7;
  int t  = bt & (TSEQ - 1);
  int tok = tokens[bt];
  float4 te = *(const float4*)(tok_emb + (size_t)tok * CDIM + c);
  float4 pe = *(const float4*)(pos_emb + (size_t)t * CDIM + c);
  float4 r;
  r.x = te.x + pe.x; r.y = te.y + pe.y; r.z = te.z + pe.z; r.w = te.w + pe.w;
  *(float4*)(x + i) = r;
}

// ------------------------------------------------- weight pack (bf16 B^T) --
__global__ __launch_bounds__(256) void packqkv_bf16(
    const float* __restrict__ Wq, const float* __restrict__ Wk,
    const float* __restrict__ Wv, u16* __restrict__ dst) {
  int idx = blockIdx.x * 256 + threadIdx.x;
  if (idx >= NL * 384 * CDIM) return;
  int c = idx & 127;
  int j = (idx >> 7) % 384;
  int l = idx / (384 * CDIM);
  int sel = j >> 7;
  int jj  = j & 127;
  int h   = jj >> 4;
  int d   = jj & 15;
  const float* W = (sel == 0) ? Wq : (sel == 1) ? Wk : Wv;
  dst[idx] = f2b(W[(((size_t)l * NH + h) * CDIM + c) * HD + d]);
}

// src[l][r][c] -> dst[l][c][r] (bf16)
__global__ __launch_bounds__(256) void transpose_cast(
    const float* __restrict__ src, u16* __restrict__ dst, int R, int C, int L) {
  int idx = blockIdx.x * 256 + threadIdx.x;
  if (idx >= L * R * C) return;
  int r = idx % R;
  int c = (idx / R) % C;
  int l = idx / (R * C);
  dst[idx] = f2b(src[((size_t)l * R + r) * C + c]);
}

// ------------------------------------------------------------ layernorm ----
__global__ __launch_bounds__(256) void ln_kernel(
    const float* __restrict__ x, const float* __restrict__ g,
    const float* __restrict__ b, u16* __restrict__ out) {
  int wid  = blockIdx.x * 4 + (threadIdx.x >> 6);
  int lane = threadIdx.x & 63;
  const float2 v = ((const float2*)(x + (size_t)wid * CDIM))[lane];
  float s = v.x + v.y;
  #pragma unroll
  for (int m = 1; m < 64; m <<= 1) s += __shfl_xor(s, m);
  float mu = s * (1.f / CDIM);
  float dx = v.x - mu, dy = v.y - mu;
  float s2 = dx * dx + dy * dy;
  #pragma unroll
  for (int m = 1; m < 64; m <<= 1) s2 += __shfl_xor(s2, m);
  float rstd = rsqrtf(s2 * (1.f / CDIM) + 1e-5f);
  float2 gg = ((const float2*)g)[lane];
  float2 bb = ((const float2*)b)[lane];
  u32 pack = (u32)f2b(dx * rstd * gg.x + bb.x) |
             ((u32)f2b(dy * rstd * gg.y + bb.y) << 16);
  ((u32*)(out + (size_t)wid * CDIM))[lane] = pack;
}

// ------------------------------------------------------------ MFMA GEMM ----
// OMODE: 0 = bf16 out, 1 = f32 out, 2 = f32 += (residual in-place)
template<int OMODE, bool BIAS, bool RELU, int BN>
__global__ __launch_bounds__(256) void gemm_mfma(
    const u16* __restrict__ A, const u16* __restrict__ Btp,
    const float* __restrict__ bias, void* __restrict__ Cout,
    int M, int N, int K) {
  constexpr int BM = 128, BK = 32, PAD = 40;
  constexpr int NF = BN / 32;
  __shared__ u16 As[BM][PAD];
  __shared__ u16 Bs[BN][PAD];
  const int tid  = threadIdx.x;
  const int lane = tid & 63;
  const int wv   = tid >> 6;
  const int wm   = wv & 1;
  const int wn   = wv >> 1;
  const int m0 = blockIdx.y * BM;
  const int n0 = blockIdx.x * BN;
  const int srow = tid >> 2;
  const int sk8  = (tid & 3) * 8;
  const int fr = lane & 15;
  const int fk = (lane >> 4) * 8;

  fv4 acc[4][NF];
  #pragma unroll
  for (int i = 0; i < 4; i++)
    #pragma unroll
    for (int j = 0; j < NF; j++) acc[i][j] = (fv4){0.f, 0.f, 0.f, 0.f};

  for (int k0 = 0; k0 < K; k0 += BK) {
    #pragma unroll
    for (int p = 0; p < 2; p++) {
      int r = srow + p * 64;
      *(uint4*)&As[r][sk8] = *(const uint4*)(A + (size_t)(m0 + r) * K + k0 + sk8);
    }
    #pragma unroll
    for (int p = 0; p < BN / 64; p++) {
      int r = srow + p * 64;
      int n = n0 + r;
      uint4 v = make_uint4(0u, 0u, 0u, 0u);
      if (n < N) v = *(const uint4*)(Btp + (size_t)n * K + k0 + sk8);
      *(uint4*)&Bs[r][sk8] = v;
    }
    __syncthreads();
    bfv8 a[4], b[NF];
    #pragma unroll
    for (int i = 0; i < 4; i++)
      a[i] = *(const bfv8*)&As[wm * 64 + i * 16 + fr][fk];
    #pragma unroll
    for (int j = 0; j < NF; j++)
      b[j] = *(const bfv8*)&Bs[wn * (BN / 2) + j * 16 + fr][fk];
    #pragma unroll
    for (int i = 0; i < 4; i++)
      #pragma unroll
      for (int j = 0; j < NF; j++)
        acc[i][j] = __builtin_amdgcn_mfma_f32_16x16x32_bf16(a[i], b[j], acc[i][j], 0, 0, 0);
    __syncthreads();
  }

  const int row0 = m0 + wm * 64;
  const int col0 = n0 + wn * (BN / 2);
  const int lr   = (lane >> 4) * 4;
  #pragma unroll
  for (int j = 0; j < NF; j++) {
    int col = col0 + j * 16 + fr;
    if (col >= N) continue;
    float bz = BIAS ? bias[col] : 0.f;
    #pragma unroll
    for (int i = 0; i < 4; i++) {
      #pragma unroll
      for (int q = 0; q < 4; q++) {
        int row = row0 + i * 16 + lr + q;
        float v = acc[i][j][q] + bz;
        if (RELU) v = fmaxf(v, 0.f);
        if (OMODE == 0)      ((u16*)Cout)[(size_t)row * N + col] = f2b(v);
        else if (OMODE == 1) ((float*)Cout)[(size_t)row * N + col] = v;
        else                 ((float*)Cout)[(size_t)row * N + col] += v;
      }
    }
  }
}

// ------------------------------------------------------- MFMA attention ----
// one workgroup per (b,h); 4 waves; each wave owns q-tiles {w,7-w,8+w,15-w}.
// Swapped QK^T: S^T tile = mfma(A=K, B=Q) -> lane holds col q=lane&15,
// rows s=4g+r. Softmax per q-column = 2 cross-lane shuffles (xor16/32).
// PV: O^T = mfma(A=V^T, B=P^T); P^T b-frag built via cvt_pk + 8 bpermutes.
__global__ __launch_bounds__(256) void attn_mfma(
    const u16* __restrict__ qkv, u16* __restrict__ out) {
  const float scale = 0.08838834764831843f;   // C^-0.5 (C=128, per reference!)
  __shared__ u16 Qs[TSEQ][40];                // dims 0..15 data, 16..31 zero
  __shared__ u16 Ks[TSEQ][40];
  __shared__ u16 Vt[HD][280];                 // V transposed: [d][s]
  const int bh = blockIdx.x;
  const int h = bh & (NH - 1);
  const int b = bh >> 3;
  const int tid = threadIdx.x;

  // ---- stage Q,K row-major (zero-padded K-dim) and V transposed ----
  #pragma unroll
  for (int p = 0; p < 2; p++) {
    int idx = tid + p * 256;
    int r  = idx >> 1;
    int c8 = (idx & 1) * 8;
    const u16* base = qkv + (size_t)(b * TSEQ + r) * 384 + h * HD + c8;
    uint4 q = *(const uint4*)(base);
    uint4 k = *(const uint4*)(base + CDIM);
    u16v8 v = *(const u16v8*)(base + 2 * CDIM);
    *(uint4*)&Qs[r][c8] = q;
    *(uint4*)&Ks[r][c8] = k;
    if (c8 == 0) {
      uint4 z = make_uint4(0u, 0u, 0u, 0u);
      *(uint4*)&Qs[r][16] = z; *(uint4*)&Qs[r][24] = z;
      *(uint4*)&Ks[r][16] = z; *(uint4*)&Ks[r][24] = z;
    }
    #pragma unroll
    for (int i = 0; i < 8; i++) Vt[c8 + i][r] = v[i];
  }
  __syncthreads();

  const int wv   = tid >> 6;
  const int lane = tid & 63;
  const int fr = lane & 15;          // A-row / B-col / D-col index
  const int g  = lane >> 4;
  const int fk = g * 8;              // fragment k-offset

  const int qts[4] = {wv, 7 - wv, 8 + wv, 15 - wv};

  #pragma unroll
  for (int qi = 0; qi < 4; qi++) {
    const int qt = qts[qi];          // wave-uniform
    bfv8 qf = *(const bfv8*)&Qs[qt * 16 + fr][fk];

    fv4 sf[16];
    #pragma unroll
    for (int st = 0; st < 16; st++) {
      if (st <= qt) {
        bfv8 kf = *(const bfv8*)&Ks[st * 16 + fr][fk];
        fv4 z = (fv4){0.f, 0.f, 0.f, 0.f};
        sf[st] = __builtin_amdgcn_mfma_f32_16x16x32_bf16(kf, qf, z, 0, 0, 0);
      }
    }

    // scale + causal mask (diagonal tile) + column max
    float mx = -3.4e38f;
    #pragma unroll
    for (int st = 0; st < 16; st++) {
      if (st <= qt) {
        #pragma unroll
        for (int r = 0; r < 4; r++) {
          float v = sf[st][r] * scale;
          if (st == qt && (4 * g + r) > fr) v = -3.4e38f;
          sf[st][r] = v;
          mx = fmaxf(mx, v);
        }
      }
    }
    mx = fmaxf(mx, __shfl_xor(mx, 16));
    mx = fmaxf(mx, __shfl_xor(mx, 32));

    float sum = 0.f;
    #pragma unroll
    for (int st = 0; st < 16; st++) {
      if (st <= qt) {
        #pragma unroll
        for (int r = 0; r < 4; r++) {
          float p = __expf(sf[st][r] - mx);
          sf[st][r] = p;
          sum += p;
        }
      }
    }
    sum += __shfl_xor(sum, 16);
    sum += __shfl_xor(sum, 32);
    const float inv = 1.f / sum;

    // PV: iterate ksteps of 32 keys (= 2 s-tiles); build P^T b-frag
    fv4 accO = (fv4){0.f, 0.f, 0.f, 0.f};
    #pragma unroll
    for (int ks = 0; ks < 8; ks++) {
      if (2 * ks <= qt) {
        u32 E0 = cvtpk(sf[2 * ks][0], sf[2 * ks][1]);
        u32 E1 = cvtpk(sf[2 * ks][2], sf[2 * ks][3]);
        u32 O0 = 0u, O1 = 0u;
        if (2 * ks + 1 <= qt) {
          O0 = cvtpk(sf[2 * ks + 1][0], sf[2 * ks + 1][1]);
          O1 = cvtpk(sf[2 * ks + 1][2], sf[2 * ks + 1][3]);
        }
        // b-frag word w holds keys s_in_kstep = 8g+2w, 8g+2w+1
        u32 w[4];
        #pragma unroll
        for (int ww = 0; ww < 4; ww++) {
          int src = (2 * (g & 1) + (ww >> 1)) * 16 + fr;
          u32 tE = __shfl((ww & 1) ? E1 : E0, src);
          u32 tO = __shfl((ww & 1) ? O1 : O0, src);
          w[ww] = (g >= 2) ? tO : tE;
        }
        uint4 uw = make_uint4(w[0], w[1], w[2], w[3]);
        bfv8 pf = __builtin_bit_cast(bfv8, uw);
        bfv8 vf = *(const bfv8*)&Vt[fr][ks * 32 + fk];
        accO = __builtin_amdgcn_mfma_f32_16x16x32_bf16(vf, pf, accO, 0, 0, 0);
      }
    }

    // O^T D-frag: col q = fr, rows d = 4g+r; scale by inv, store 8B
    int q_glob = qt * 16 + fr;
    u32 lo = cvtpk(accO[0] * inv, accO[1] * inv);
    u32 hi = cvtpk(accO[2] * inv, accO[3] * inv);
    uint2 st2 = make_uint2(lo, hi);
    *(uint2*)(out + (size_t)(b * TSEQ + q_glob) * CDIM + h * HD + 4 * g) = st2;
  }
}

// ----------------------------------------------------------------- host ----
extern "C" void kernel_launch(void* const* d_in, const int* in_sizes, int n_in,
                              void* d_out, int out_size, void* d_ws, size_t ws_size,
                              hipStream_t stream) {
  const int*   tokens  = (const int*)  d_in[0];
  const float* tok_emb = (const float*)d_in[1];
  const float* pos_emb = (const float*)d_in[2];
  const float* Wq      = (const float*)d_in[3];
  const float* Wk      = (const float*)d_in[4];
  const float* Wv      = (const float*)d_in[5];
  const float* Wproj   = (const float*)d_in[6];
  const float* bproj   = (const float*)d_in[7];
  const float* ln1_g   = (const float*)d_in[8];
  const float* ln1_b   = (const float*)d_in[9];
  const float* ln2_g   = (const float*)d_in[10];
  const float* ln2_b   = (const float*)d_in[11];
  const float* W1      = (const float*)d_in[12];
  const float* b1      = (const float*)d_in[13];
  const float* W2      = (const float*)d_in[14];
  const float* b2      = (const float*)d_in[15];
  const float* lnf_g   = (const float*)d_in[16];
  const float* lnf_b   = (const float*)d_in[17];
  const float* Wlm     = (const float*)d_in[18];
  const float* blm     = (const float*)d_in[19];
  float* out = (float*)d_out;

  char* W = (char*)d_ws;
  float* x    = (float*)(W);                   // 16384*128 f32      (8 MB)
  u16*   xn   = (u16*)  (W + 8388608);         // 16384*128 bf16     (4 MB)
  u16*   qkvb = (u16*)  (W + 12582912);        // 16384*384 bf16     (12 MB)
  u16*   att  = (u16*)  (W + 25165824);        // 16384*128 bf16     (4 MB)
  u16*   hbuf = (u16*)  (W + 29360128);        // 16384*512 bf16     (16 MB)
  u16*   wqkv = (u16*)  (W + 46137344);        // 6*384*128
  u16*   wpj  = (u16*)  (W + 46727168);        // 6*128*128
  u16*   w1t  = (u16*)  (W + 46923776);        // 6*512*128
  u16*   w2t  = (u16*)  (W + 47710208);        // 6*128*512
  u16*   wlmt = (u16*)  (W + 48496640);        // 3149*128

  packqkv_bf16<<<(NL * 384 * CDIM + 255) / 256, 256, 0, stream>>>(Wq, Wk, Wv, wqkv);
  transpose_cast<<<(NL * CDIM * CDIM + 255) / 256, 256, 0, stream>>>(Wproj, wpj, CDIM, CDIM, NL);
  transpose_cast<<<(NL * CDIM * FFD + 255) / 256, 256, 0, stream>>>(W1, w1t, CDIM, FFD, NL);
  transpose_cast<<<(NL * FFD * CDIM + 255) / 256, 256, 0, stream>>>(W2, w2t, FFD, CDIM, NL);
  transpose_cast<<<(CDIM * NV + 255) / 256, 256, 0, stream>>>(Wlm, wlmt, CDIM, NV, 1);
  embed_kernel<<<(BT * CDIM / 4 + 255) / 256, 256, 0, stream>>>(tokens, tok_emb, pos_emb, x);

  for (int l = 0; l < NL; l++) {
    ln_kernel<<<BT / 4, 256, 0, stream>>>(x, ln1_g + l * CDIM, ln1_b + l * CDIM, xn);
    gemm_mfma<0, false, false, 128><<<dim3(3, BT / 128), 256, 0, stream>>>(
        xn, wqkv + (size_t)l * 384 * CDIM, nullptr, qkvb, BT, 384, CDIM);
    attn_mfma<<<NBAT * NH, 256, 0, stream>>>(qkvb, att);
    gemm_mfma<2, true, false, 64><<<dim3(2, BT / 128), 256, 0, stream>>>(
        att, wpj + (size_t)l * CDIM * CDIM, bproj + l * CDIM, x, BT, CDIM, CDIM);
    ln_kernel<<<BT / 4, 256, 0, stream>>>(x, ln2_g + l * CDIM, ln2_b + l * CDIM, xn);
    gemm_mfma<0, true, true, 128><<<dim3(4, BT / 128), 256, 0, stream>>>(
        xn, w1t + (size_t)l * FFD * CDIM, b1 + l * FFD, hbuf, BT, FFD, CDIM);
    gemm_mfma<2, true, false, 64><<<dim3(2, BT / 128), 256, 0, stream>>>(
        hbuf, w2t + (size_t)l * CDIM * FFD, b2 + l * CDIM, x, BT, CDIM, FFD);
  }
  ln_kernel<<<BT / 4, 256, 0, stream>>>(x, lnf_g, lnf_b, xn);
  gemm_mfma<1, true, false, 128><<<dim3((NV + 127) / 128, BT / 128), 256, 0, stream>>>(
      xn, wlmt, blm, out, BT, NV, CDIM);
}

// Round 6
// 847.368 us; speedup vs baseline: 6.2458x; 1.0112x over previous
//
#include <hip/hip_runtime.h>
#include <hip/hip_bf16.h>
#include <math.h>

#define BT   16384   // B*T
#define CDIM 128
#define TSEQ 256
#define NBAT 64
#define NH   8
#define HD   16
#define NL   6
#define FFD  512
#define NV   3149

typedef __bf16 bfv8 __attribute__((ext_vector_type(8)));
typedef float  fv4  __attribute__((ext_vector_type(4)));
typedef short  s4   __attribute__((ext_vector_type(4)));
typedef unsigned short u16;
typedef unsigned int   u32;
typedef u16 u16v8 __attribute__((ext_vector_type(8)));

__device__ __forceinline__ u16 f2b(float f) {
  u32 u = __builtin_bit_cast(u32, f);
  u += 0x7FFFu + ((u >> 16) & 1u);        // round-to-nearest-even
  return (u16)(u >> 16);
}
__device__ __forceinline__ u32 cvtpk(float lo, float hi) {
  u32 r;
  asm("v_cvt_pk_bf16_f32 %0, %1, %2" : "=v"(r) : "v"(lo), "v"(hi));
  return r;
}
__device__ __forceinline__ fv4 mfma16(s4 a, s4 b, fv4 c) {
#if __has_builtin(__builtin_amdgcn_mfma_f32_16x16x16bf16_1k)
  return __builtin_amdgcn_mfma_f32_16x16x16bf16_1k(a, b, c, 0, 0, 0);
#else
  fv4 d;
  asm volatile("v_mfma_f32_16x16x16_bf16 %0, %1, %2, %3"
               : "=v"(d) : "v"(a), "v"(b), "v"(c));
  return d;
#endif
}

// ---------------------------------------------------------------- embed ----
__global__ __launch_bounds__(256) void embed_kernel(
    const int* __restrict__ tokens, const float* __restrict__ tok_emb,
    const float* __restrict__ pos_emb, float* __restrict__ x) {
  int i4 = blockIdx.x * 256 + threadIdx.x;
  if (i4 >= BT * CDIM / 4) return;
  int i  = i4 * 4;
  int c  = i & (CDIM - 1);
  int bt = i >> 7;
  int t  = bt & (TSEQ - 1);
  int tok = tokens[bt];
  float4 te = *(const float4*)(tok_emb + (size_t)tok * CDIM + c);
  float4 pe = *(const float4*)(pos_emb + (size_t)t * CDIM + c);
  float4 r;
  r.x = te.x + pe.x; r.y = te.y + pe.y; r.z = te.z + pe.z; r.w = te.w + pe.w;
  *(float4*)(x + i) = r;
}

// ------------------------------------------------- weight pack (bf16 B^T) --
__global__ __launch_bounds__(256) void packqkv_bf16(
    const float* __restrict__ Wq, const float* __restrict__ Wk,
    const float* __restrict__ Wv, u16* __restrict__ dst) {
  int idx = blockIdx.x * 256 + threadIdx.x;
  if (idx >= NL * 384 * CDIM) return;
  int c = idx & 127;
  int j = (idx >> 7) % 384;
  int l = idx / (384 * CDIM);
  int sel = j >> 7;
  int jj  = j & 127;
  int h   = jj >> 4;
  int d   = jj & 15;
  const float* W = (sel == 0) ? Wq : (sel == 1) ? Wk : Wv;
  dst[idx] = f2b(W[(((size_t)l * NH + h) * CDIM + c) * HD + d]);
}

// tiled transpose: dst[l][c][r] = bf16(src[l][r][c]); coalesced both sides
__global__ __launch_bounds__(256) void transpose_cast_t(
    const float* __restrict__ src, u16* __restrict__ dst, int R, int C) {
  __shared__ float tile[32][33];
  int l  = blockIdx.z;
  int r0 = blockIdx.y * 32, c0 = blockIdx.x * 32;
  int tr = threadIdx.x >> 5, tc = threadIdx.x & 31;
  #pragma unroll
  for (int p = 0; p < 4; p++) {
    int r = r0 + tr + p * 8, c = c0 + tc;
    if (r < R && c < C) tile[tr + p * 8][tc] = src[((size_t)l * R + r) * C + c];
  }
  __syncthreads();
  #pragma unroll
  for (int p = 0; p < 4; p++) {
    int c = c0 + tr + p * 8, r = r0 + tc;
    if (r < R && c < C) dst[((size_t)l * C + c) * R + r] = f2b(tile[tc][tr + p * 8]);
  }
}

// ------------------------------------------------------------ layernorm ----
__global__ __launch_bounds__(256) void ln_kernel(
    const float* __restrict__ x, const float* __restrict__ g,
    const float* __restrict__ b, u16* __restrict__ out) {
  int wid  = blockIdx.x * 4 + (threadIdx.x >> 6);
  int lane = threadIdx.x & 63;
  const float2 v = ((const float2*)(x + (size_t)wid * CDIM))[lane];
  float s = v.x + v.y;
  #pragma unroll
  for (int m = 1; m < 64; m <<= 1) s += __shfl_xor(s, m);
  float mu = s * (1.f / CDIM);
  float dx = v.x - mu, dy = v.y - mu;
  float s2 = dx * dx + dy * dy;
  #pragma unroll
  for (int m = 1; m < 64; m <<= 1) s2 += __shfl_xor(s2, m);
  float rstd = rsqrtf(s2 * (1.f / CDIM) + 1e-5f);
  float2 gg = ((const float2*)g)[lane];
  float2 bb = ((const float2*)b)[lane];
  u32 pack = (u32)f2b(dx * rstd * gg.x + bb.x) |
             ((u32)f2b(dy * rstd * gg.y + bb.y) << 16);
  ((u32*)(out + (size_t)wid * CDIM))[lane] = pack;
}

// ------------------------------------------------------------ MFMA GEMM ----
// OMODE: 0 = bf16 out, 1 = f32 out, 2 = f32 += (residual in-place)
template<int OMODE, bool BIAS, bool RELU, int BN>
__global__ __launch_bounds__(256) void gemm_mfma(
    const u16* __restrict__ A, const u16* __restrict__ Btp,
    const float* __restrict__ bias, void* __restrict__ Cout,
    int M, int N, int K) {
  constexpr int BM = 128, BK = 32, PAD = 40;
  constexpr int NF = BN / 32;
  __shared__ u16 As[BM][PAD];
  __shared__ u16 Bs[BN][PAD];
  const int tid  = threadIdx.x;
  const int lane = tid & 63;
  const int wv   = tid >> 6;
  const int wm   = wv & 1;
  const int wn   = wv >> 1;
  const int m0 = blockIdx.y * BM;
  const int n0 = blockIdx.x * BN;
  const int srow = tid >> 2;
  const int sk8  = (tid & 3) * 8;
  const int fr = lane & 15;
  const int fk = (lane >> 4) * 8;

  fv4 acc[4][NF];
  #pragma unroll
  for (int i = 0; i < 4; i++)
    #pragma unroll
    for (int j = 0; j < NF; j++) acc[i][j] = (fv4){0.f, 0.f, 0.f, 0.f};

  for (int k0 = 0; k0 < K; k0 += BK) {
    #pragma unroll
    for (int p = 0; p < 2; p++) {
      int r = srow + p * 64;
      *(uint4*)&As[r][sk8] = *(const uint4*)(A + (size_t)(m0 + r) * K + k0 + sk8);
    }
    #pragma unroll
    for (int p = 0; p < BN / 64; p++) {
      int r = srow + p * 64;
      int n = n0 + r;
      uint4 v = make_uint4(0u, 0u, 0u, 0u);
      if (n < N) v = *(const uint4*)(Btp + (size_t)n * K + k0 + sk8);
      *(uint4*)&Bs[r][sk8] = v;
    }
    __syncthreads();
    bfv8 a[4], b[NF];
    #pragma unroll
    for (int i = 0; i < 4; i++)
      a[i] = *(const bfv8*)&As[wm * 64 + i * 16 + fr][fk];
    #pragma unroll
    for (int j = 0; j < NF; j++)
      b[j] = *(const bfv8*)&Bs[wn * (BN / 2) + j * 16 + fr][fk];
    #pragma unroll
    for (int i = 0; i < 4; i++)
      #pragma unroll
      for (int j = 0; j < NF; j++)
        acc[i][j] = __builtin_amdgcn_mfma_f32_16x16x32_bf16(a[i], b[j], acc[i][j], 0, 0, 0);
    __syncthreads();
  }

  const int row0 = m0 + wm * 64;
  const int col0 = n0 + wn * (BN / 2);
  const int lr   = (lane >> 4) * 4;
  #pragma unroll
  for (int j = 0; j < NF; j++) {
    int col = col0 + j * 16 + fr;
    if (col >= N) continue;
    float bz = BIAS ? bias[col] : 0.f;
    #pragma unroll
    for (int i = 0; i < 4; i++) {
      #pragma unroll
      for (int q = 0; q < 4; q++) {
        int row = row0 + i * 16 + lr + q;
        float v = acc[i][j][q] + bz;
        if (RELU) v = fmaxf(v, 0.f);
        if (OMODE == 0)      ((u16*)Cout)[(size_t)row * N + col] = f2b(v);
        else if (OMODE == 1) ((float*)Cout)[(size_t)row * N + col] = v;
        else                 ((float*)Cout)[(size_t)row * N + col] += v;
      }
    }
  }
}

// ---------------------------------------------- fused LayerNorm + GEMM -----
// C[M,N](bf16) = epi(LN(X[M,128]) @ Bt[N,128]^T); K=128 fixed; BM=BN=128
template<bool BIAS, bool RELU>
__global__ __launch_bounds__(256) void gemm_ln_mfma(
    const float* __restrict__ X, const u16* __restrict__ Btp,
    const float* __restrict__ lng, const float* __restrict__ lnb,
    const float* __restrict__ bias, u16* __restrict__ Cout,
    int M, int N) {
  constexpr int BM = 128, BN = 128, BK = 32;
  __shared__ u16 As[BM][136];              // full K=128 + pad (272B rows)
  __shared__ u16 Bs[BN][40];
  const int tid  = threadIdx.x;
  const int lane = tid & 63;
  const int wv   = tid >> 6;
  const int wm   = wv & 1;
  const int wn   = wv >> 1;
  const int m0 = blockIdx.y * BM;
  const int n0 = blockIdx.x * BN;
  const int fr = lane & 15;
  const int fk = (lane >> 4) * 8;

  // LN prologue: wave wv owns rows [wv*32, wv*32+32); 2 rows/iter
  {
    const int l32  = lane & 31;
    const int rsel = lane >> 5;
    float4 gg = *(const float4*)(lng + l32 * 4);
    float4 bb = *(const float4*)(lnb + l32 * 4);
    #pragma unroll 4
    for (int it = 0; it < 16; it++) {
      int r = wv * 32 + it * 2 + rsel;
      float4 v = *(const float4*)(X + (size_t)(m0 + r) * 128 + l32 * 4);
      float s = (v.x + v.y) + (v.z + v.w);
      #pragma unroll
      for (int m = 1; m < 32; m <<= 1) s += __shfl_xor(s, m);
      float mu = s * (1.f / 128.f);
      float dx = v.x - mu, dy = v.y - mu, dz = v.z - mu, dw = v.w - mu;
      float s2 = (dx * dx + dy * dy) + (dz * dz + dw * dw);
      #pragma unroll
      for (int m = 1; m < 32; m <<= 1) s2 += __shfl_xor(s2, m);
      float rstd = rsqrtf(s2 * (1.f / 128.f) + 1e-5f);
      u32 p0 = cvtpk(dx * rstd * gg.x + bb.x, dy * rstd * gg.y + bb.y);
      u32 p1 = cvtpk(dz * rstd * gg.z + bb.z, dw * rstd * gg.w + bb.w);
      *(uint2*)&As[r][l32 * 4] = make_uint2(p0, p1);
    }
  }

  fv4 acc[4][4];
  #pragma unroll
  for (int i = 0; i < 4; i++)
    #pragma unroll
    for (int j = 0; j < 4; j++) acc[i][j] = (fv4){0.f, 0.f, 0.f, 0.f};

  for (int k0 = 0; k0 < 128; k0 += BK) {
    #pragma unroll
    for (int p = 0; p < 2; p++) {
      int ch = tid + p * 256;
      int row = ch >> 2, c8 = (ch & 3) * 8;
      *(uint4*)&Bs[row][c8] = *(const uint4*)(Btp + (size_t)(n0 + row) * 128 + k0 + c8);
    }
    __syncthreads();
    bfv8 a[4], b[4];
    #pragma unroll
    for (int i = 0; i < 4; i++)
      a[i] = *(const bfv8*)&As[wm * 64 + i * 16 + fr][k0 + fk];
    #pragma unroll
    for (int j = 0; j < 4; j++)
      b[j] = *(const bfv8*)&Bs[wn * 64 + j * 16 + fr][fk];
    #pragma unroll
    for (int i = 0; i < 4; i++)
      #pragma unroll
      for (int j = 0; j < 4; j++)
        acc[i][j] = __builtin_amdgcn_mfma_f32_16x16x32_bf16(a[i], b[j], acc[i][j], 0, 0, 0);
    __syncthreads();
  }

  const int row0 = m0 + wm * 64;
  const int col0 = n0 + wn * 64;
  const int lr   = (lane >> 4) * 4;
  #pragma unroll
  for (int j = 0; j < 4; j++) {
    int col = col0 + j * 16 + fr;
    float bz = BIAS ? bias[col] : 0.f;
    #pragma unroll
    for (int i = 0; i < 4; i++) {
      #pragma unroll
      for (int q = 0; q < 4; q++) {
        int row = row0 + i * 16 + lr + q;
        float v = acc[i][j][q] + bz;
        if (RELU) v = fmaxf(v, 0.f);
        Cout[(size_t)row * N + col] = f2b(v);
      }
    }
  }
}

// ------------------------------------------------------- MFMA attention ----
// one block per (b, h, qhalf); 4 waves; wave handles q-tiles {w, 7-w} of its
// half. 16x16x16 MFMA (K = head_size = 16): S^T = mfma(K,Q) leaves each lane
// holding P rows 4g..4g+3 of col q=fr -> EXACTLY the PV B-fragment (k=4g+j,
// col=fr). Zero cross-lane traffic in PV.
__global__ __launch_bounds__(256) void attn_mfma(
    const u16* __restrict__ qkv, u16* __restrict__ out) {
  const float scale = 0.08838834764831843f;   // C^-0.5 (C=128, per reference!)
  __shared__ u16 Qs[128][20];                 // this half's q rows
  __shared__ u16 Ks[TSEQ][20];
  __shared__ u16 Vt[HD][280];                 // V transposed [d][s]
  const int blk = blockIdx.x;
  const int qh = blk & 1;
  const int h  = (blk >> 1) & (NH - 1);
  const int b  = blk >> 4;
  const int tid = threadIdx.x;

  #pragma unroll
  for (int p = 0; p < 2; p++) {
    int idx = tid + p * 256;
    int r  = idx >> 1;
    int c8 = (idx & 1) * 8;
    const u16* base = qkv + (size_t)(b * TSEQ + r) * 384 + h * HD + c8;
    uint4 k  = *(const uint4*)(base + CDIM);
    u16v8 v  = *(const u16v8*)(base + 2 * CDIM);
    *(uint4*)&Ks[r][c8] = k;
    #pragma unroll
    for (int i = 0; i < 8; i++) Vt[c8 + i][r] = v[i];
  }
  {
    int r  = tid >> 1;
    int c8 = (tid & 1) * 8;
    const u16* base = qkv + (size_t)(b * TSEQ + qh * 128 + r) * 384 + h * HD + c8;
    *(uint4*)&Qs[r][c8] = *(const uint4*)(base);
  }
  __syncthreads();

  const int wv   = tid >> 6;
  const int lane = tid & 63;
  const int fr = lane & 15;
  const int g  = lane >> 4;

  #pragma unroll 1
  for (int qi = 0; qi < 2; qi++) {
    const int qt = qh * 8 + (qi ? (7 - wv) : wv);     // wave-uniform
    const int qr = (qt - qh * 8) * 16 + fr;
    s4 qf = *(const s4*)&Qs[qr][g * 4];

    fv4 sf[16];
    #pragma unroll
    for (int st = 0; st < 16; st++) {
      if (st <= qt) {
        s4 kf = *(const s4*)&Ks[st * 16 + fr][g * 4];
        sf[st] = mfma16(kf, qf, (fv4){0.f, 0.f, 0.f, 0.f});
      }
    }

    float mx = -3.4e38f;
    #pragma unroll
    for (int st = 0; st < 16; st++) {
      if (st <= qt) {
        #pragma unroll
        for (int r = 0; r < 4; r++) {
          float v = sf[st][r] * scale;
          if (st == qt && (4 * g + r) > fr) v = -3.4e38f;
          sf[st][r] = v;
          mx = fmaxf(mx, v);
        }
      }
    }
    mx = fmaxf(mx, __shfl_xor(mx, 16));
    mx = fmaxf(mx, __shfl_xor(mx, 32));

    float sum = 0.f;
    uint2 pk[16];
    #pragma unroll
    for (int st = 0; st < 16; st++) {
      if (st <= qt) {
        float e0 = __expf(sf[st][0] - mx), e1 = __expf(sf[st][1] - mx);
        float e2 = __expf(sf[st][2] - mx), e3 = __expf(sf[st][3] - mx);
        sum += (e0 + e1) + (e2 + e3);
        pk[st] = make_uint2(cvtpk(e0, e1), cvtpk(e2, e3));
      }
    }
    sum += __shfl_xor(sum, 16);
    sum += __shfl_xor(sum, 32);
    const float inv = 1.f / sum;

    fv4 accO = (fv4){0.f, 0.f, 0.f, 0.f};
    #pragma unroll
    for (int st = 0; st < 16; st++) {
      if (st <= qt) {
        s4 vf = *(const s4*)&Vt[fr][st * 16 + g * 4];
        s4 pf = __builtin_bit_cast(s4, pk[st]);
        accO = mfma16(vf, pf, accO);
      }
    }

    const int q_glob = qt * 16 + fr;
    u32 lo = cvtpk(accO[0] * inv, accO[1] * inv);
    u32 hi = cvtpk(accO[2] * inv, accO[3] * inv);
    *(uint2*)(out + (size_t)(b * TSEQ + q_glob) * CDIM + h * HD + 4 * g) =
        make_uint2(lo, hi);
  }
}

// ----------------------------------------------------------------- host ----
extern "C" void kernel_launch(void* const* d_in, const int* in_sizes, int n_in,
                              void* d_out, int out_size, void* d_ws, size_t ws_size,
                              hipStream_t stream) {
  const int*   tokens  = (const int*)  d_in[0];
  const float* tok_emb = (const float*)d_in[1];
  const float* pos_emb = (const float*)d_in[2];
  const float* Wq      = (const float*)d_in[3];
  const float* Wk      = (const float*)d_in[4];
  const float* Wv      = (const float*)d_in[5];
  const float* Wproj   = (const float*)d_in[6];
  const float* bproj   = (const float*)d_in[7];
  const float* ln1_g   = (const float*)d_in[8];
  const float* ln1_b   = (const float*)d_in[9];
  const float* ln2_g   = (const float*)d_in[10];
  const float* ln2_b   = (const float*)d_in[11];
  const float* W1      = (const float*)d_in[12];
  const float* b1      = (const float*)d_in[13];
  const float* W2      = (const float*)d_in[14];
  const float* b2      = (const float*)d_in[15];
  const float* lnf_g   = (const float*)d_in[16];
  const float* lnf_b   = (const float*)d_in[17];
  const float* Wlm     = (const float*)d_in[18];
  const float* blm     = (const float*)d_in[19];
  float* out = (float*)d_out;

  char* W = (char*)d_ws;
  float* x    = (float*)(W);                   // 16384*128 f32      (8 MB)
  u16*   xn   = (u16*)  (W + 8388608);         // 16384*128 bf16     (4 MB)
  u16*   qkvb = (u16*)  (W + 12582912);        // 16384*384 bf16     (12 MB)
  u16*   att  = (u16*)  (W + 25165824);        // 16384*128 bf16     (4 MB)
  u16*   hbuf = (u16*)  (W + 29360128);        // 16384*512 bf16     (16 MB)
  u16*   wqkv = (u16*)  (W + 46137344);        // 6*384*128
  u16*   wpj  = (u16*)  (W + 46727168);        // 6*128*128
  u16*   w1t  = (u16*)  (W + 46923776);        // 6*512*128
  u16*   w2t  = (u16*)  (W + 47710208);        // 6*128*512
  u16*   wlmt = (u16*)  (W + 48496640);        // 3149*128

  packqkv_bf16<<<(NL * 384 * CDIM + 255) / 256, 256, 0, stream>>>(Wq, Wk, Wv, wqkv);
  transpose_cast_t<<<dim3(4, 4, NL), 256, 0, stream>>>(Wproj, wpj, CDIM, CDIM);
  transpose_cast_t<<<dim3(16, 4, NL), 256, 0, stream>>>(W1, w1t, CDIM, FFD);
  transpose_cast_t<<<dim3(4, 16, NL), 256, 0, stream>>>(W2, w2t, FFD, CDIM);
  transpose_cast_t<<<dim3((NV + 31) / 32, 4, 1), 256, 0, stream>>>(Wlm, wlmt, CDIM, NV);
  embed_kernel<<<(BT * CDIM / 4 + 255) / 256, 256, 0, stream>>>(tokens, tok_emb, pos_emb, x);

  for (int l = 0; l < NL; l++) {
    gemm_ln_mfma<false, false><<<dim3(3, BT / 128), 256, 0, stream>>>(
        x, wqkv + (size_t)l * 384 * CDIM, ln1_g + l * CDIM, ln1_b + l * CDIM,
        nullptr, qkvb, BT, 384);
    attn_mfma<<<NBAT * NH * 2, 256, 0, stream>>>(qkvb, att);
    gemm_mfma<2, true, false, 64><<<dim3(2, BT / 128), 256, 0, stream>>>(
        att, wpj + (size_t)l * CDIM * CDIM, bproj + l * CDIM, x, BT, CDIM, CDIM);
    gemm_ln_mfma<true, true><<<dim3(4, BT / 128), 256, 0, stream>>>(
        x, w1t + (size_t)l * FFD * CDIM, ln2_g + l * CDIM, ln2_b + l * CDIM,
        b1 + l * FFD, hbuf, BT, FFD);
    gemm_mfma<2, true, false, 64><<<dim3(2, BT / 128), 256, 0, stream>>>(
        hbuf, w2t + (size_t)l * CDIM * FFD, b2 + l * CDIM, x, BT, CDIM, FFD);
  }
  ln_kernel<<<BT / 4, 256, 0, stream>>>(x, lnf_g, lnf_b, xn);
  gemm_mfma<1, true, false, 128><<<dim3((NV + 127) / 128, BT / 128), 256, 0, stream>>>(
      xn, wlmt, blm, out, BT, NV, CDIM);
}

// Round 7
// 758.337 us; speedup vs baseline: 6.9791x; 1.1174x over previous
//
#include <hip/hip_runtime.h>
#include <hip/hip_bf16.h>
#include <math.h>

#define BT   16384   // B*T
#define CDIM 128
#define TSEQ 256
#define NBAT 64
#define NH   8
#define HD   16
#define NL   6
#define FFD  512
#define NV   3149

typedef __bf16 bfv8 __attribute__((ext_vector_type(8)));
typedef float  fv4  __attribute__((ext_vector_type(4)));
typedef short  s4   __attribute__((ext_vector_type(4)));
typedef unsigned short u16;
typedef unsigned int   u32;
typedef u16 u16v8 __attribute__((ext_vector_type(8)));

__device__ __forceinline__ u16 f2b(float f) {
  u32 u = __builtin_bit_cast(u32, f);
  u += 0x7FFFu + ((u >> 16) & 1u);        // round-to-nearest-even
  return (u16)(u >> 16);
}
__device__ __forceinline__ u32 cvtpk(float lo, float hi) {
  u32 r;
  asm("v_cvt_pk_bf16_f32 %0, %1, %2" : "=v"(r) : "v"(lo), "v"(hi));
  return r;
}
__device__ __forceinline__ fv4 mfma16(s4 a, s4 b, fv4 c) {
#if __has_builtin(__builtin_amdgcn_mfma_f32_16x16x16bf16_1k)
  return __builtin_amdgcn_mfma_f32_16x16x16bf16_1k(a, b, c, 0, 0, 0);
#else
  fv4 d;
  asm volatile("v_mfma_f32_16x16x16_bf16 %0, %1, %2, %3"
               : "=v"(d) : "v"(a), "v"(b), "v"(c));
  return d;
#endif
}

// ---------------------------------------------------------------- embed ----
__global__ __launch_bounds__(256) void embed_kernel(
    const int* __restrict__ tokens, const float* __restrict__ tok_emb,
    const float* __restrict__ pos_emb, float* __restrict__ x) {
  int i4 = blockIdx.x * 256 + threadIdx.x;
  if (i4 >= BT * CDIM / 4) return;
  int i  = i4 * 4;
  int c  = i & (CDIM - 1);
  int bt = i >> 7;
  int t  = bt & (TSEQ - 1);
  int tok = tokens[bt];
  float4 te = *(const float4*)(tok_emb + (size_t)tok * CDIM + c);
  float4 pe = *(const float4*)(pos_emb + (size_t)t * CDIM + c);
  float4 r;
  r.x = te.x + pe.x; r.y = te.y + pe.y; r.z = te.z + pe.z; r.w = te.w + pe.w;
  *(float4*)(x + i) = r;
}

// ------------------------------------------------- weight pack (bf16 B^T) --
__global__ __launch_bounds__(256) void packqkv_bf16(
    const float* __restrict__ Wq, const float* __restrict__ Wk,
    const float* __restrict__ Wv, u16* __restrict__ dst) {
  int idx = blockIdx.x * 256 + threadIdx.x;
  if (idx >= NL * 384 * CDIM) return;
  int c = idx & 127;
  int j = (idx >> 7) % 384;
  int l = idx / (384 * CDIM);
  int sel = j >> 7;
  int jj  = j & 127;
  int h   = jj >> 4;
  int d   = jj & 15;
  const float* W = (sel == 0) ? Wq : (sel == 1) ? Wk : Wv;
  dst[idx] = f2b(W[(((size_t)l * NH + h) * CDIM + c) * HD + d]);
}

// tiled transpose: dst[l][c][r] = bf16(src[l][r][c]); coalesced both sides
__global__ __launch_bounds__(256) void transpose_cast_t(
    const float* __restrict__ src, u16* __restrict__ dst, int R, int C) {
  __shared__ float tile[32][33];
  int l  = blockIdx.z;
  int r0 = blockIdx.y * 32, c0 = blockIdx.x * 32;
  int tr = threadIdx.x >> 5, tc = threadIdx.x & 31;
  #pragma unroll
  for (int p = 0; p < 4; p++) {
    int r = r0 + tr + p * 8, c = c0 + tc;
    if (r < R && c < C) tile[tr + p * 8][tc] = src[((size_t)l * R + r) * C + c];
  }
  __syncthreads();
  #pragma unroll
  for (int p = 0; p < 4; p++) {
    int c = c0 + tr + p * 8, r = r0 + tc;
    if (r < R && c < C) dst[((size_t)l * C + c) * R + r] = f2b(tile[tc][tr + p * 8]);
  }
}

// ------------------------------------------------------------ MFMA GEMM ----
// C[M,N] = epi(A[M,K] @ Bt[N,K]^T); OMODE: 0 bf16, 1 f32, 2 f32 += in-place
template<int OMODE, bool BIAS, bool RELU, int BM, int BN>
__global__ __launch_bounds__(256) void gemm_mfma(
    const u16* __restrict__ A, const u16* __restrict__ Btp,
    const float* __restrict__ bias, void* __restrict__ Cout,
    int M, int N, int K) {
  constexpr int BK = 32, PAD = 40;
  constexpr int MI = BM / 32;              // m-frags per wave
  constexpr int NF = BN / 32;              // n-frags per wave
  __shared__ u16 As[BM][PAD];
  __shared__ u16 Bs[BN][PAD];
  const int tid  = threadIdx.x;
  const int lane = tid & 63;
  const int wv   = tid >> 6;
  const int wm   = wv & 1;
  const int wn   = wv >> 1;
  const int m0 = blockIdx.y * BM;
  const int n0 = blockIdx.x * BN;
  const int srow = tid >> 2;
  const int sk8  = (tid & 3) * 8;
  const int fr = lane & 15;
  const int fk = (lane >> 4) * 8;

  fv4 acc[MI][NF];
  #pragma unroll
  for (int i = 0; i < MI; i++)
    #pragma unroll
    for (int j = 0; j < NF; j++) acc[i][j] = (fv4){0.f, 0.f, 0.f, 0.f};

  for (int k0 = 0; k0 < K; k0 += BK) {
    #pragma unroll
    for (int p = 0; p < BM / 64; p++) {
      int r = srow + p * 64;
      *(uint4*)&As[r][sk8] = *(const uint4*)(A + (size_t)(m0 + r) * K + k0 + sk8);
    }
    #pragma unroll
    for (int p = 0; p < BN / 64; p++) {
      int r = srow + p * 64;
      int n = n0 + r;
      uint4 v = make_uint4(0u, 0u, 0u, 0u);
      if (n < N) v = *(const uint4*)(Btp + (size_t)n * K + k0 + sk8);
      *(uint4*)&Bs[r][sk8] = v;
    }
    __syncthreads();
    bfv8 a[MI], b[NF];
    #pragma unroll
    for (int i = 0; i < MI; i++)
      a[i] = *(const bfv8*)&As[wm * (BM / 2) + i * 16 + fr][fk];
    #pragma unroll
    for (int j = 0; j < NF; j++)
      b[j] = *(const bfv8*)&Bs[wn * (BN / 2) + j * 16 + fr][fk];
    #pragma unroll
    for (int i = 0; i < MI; i++)
      #pragma unroll
      for (int j = 0; j < NF; j++)
        acc[i][j] = __builtin_amdgcn_mfma_f32_16x16x32_bf16(a[i], b[j], acc[i][j], 0, 0, 0);
    __syncthreads();
  }

  const int row0 = m0 + wm * (BM / 2);
  const int col0 = n0 + wn * (BN / 2);
  const int lr   = (lane >> 4) * 4;
  #pragma unroll
  for (int j = 0; j < NF; j++) {
    int col = col0 + j * 16 + fr;
    if (col >= N) continue;
    float bz = BIAS ? bias[col] : 0.f;
    #pragma unroll
    for (int i = 0; i < MI; i++) {
      #pragma unroll
      for (int q = 0; q < 4; q++) {
        int row = row0 + i * 16 + lr + q;
        float v = acc[i][j][q] + bz;
        if (RELU) v = fmaxf(v, 0.f);
        if (OMODE == 0)      ((u16*)Cout)[(size_t)row * N + col] = f2b(v);
        else if (OMODE == 1) ((float*)Cout)[(size_t)row * N + col] = v;
        else                 ((float*)Cout)[(size_t)row * N + col] += v;
      }
    }
  }
}

// ---------------------------------------------- fused LayerNorm + GEMM -----
// C[M,N] = epi(LN(X[M,128]) @ Bt[N,128]^T); K=128 fixed
template<int OMODE, bool BIAS, bool RELU, int BM, int BN>
__global__ __launch_bounds__(256) void gemm_ln_mfma(
    const float* __restrict__ X, const u16* __restrict__ Btp,
    const float* __restrict__ lng, const float* __restrict__ lnb,
    const float* __restrict__ bias, void* __restrict__ Cout,
    int M, int N) {
  constexpr int BK = 32;
  constexpr int MI = BM / 32;
  constexpr int NF = BN / 32;
  __shared__ u16 As[BM][136];              // full K=128 + pad
  __shared__ u16 Bs[BN][40];
  const int tid  = threadIdx.x;
  const int lane = tid & 63;
  const int wv   = tid >> 6;
  const int wm   = wv & 1;
  const int wn   = wv >> 1;
  const int m0 = blockIdx.y * BM;
  const int n0 = blockIdx.x * BN;
  const int fr = lane & 15;
  const int fk = (lane >> 4) * 8;

  // LN prologue: 8 half-waves cover BM rows, one row per half-wave-iter
  {
    const int l32  = lane & 31;
    const int rsel = lane >> 5;
    float4 gg = *(const float4*)(lng + l32 * 4);
    float4 bb = *(const float4*)(lnb + l32 * 4);
    #pragma unroll 2
    for (int it = 0; it < BM / 8; it++) {
      int r = it * 8 + wv * 2 + rsel;
      float4 v = *(const float4*)(X + (size_t)(m0 + r) * 128 + l32 * 4);
      float s = (v.x + v.y) + (v.z + v.w);
      #pragma unroll
      for (int m = 1; m < 32; m <<= 1) s += __shfl_xor(s, m);
      float mu = s * (1.f / 128.f);
      float dx = v.x - mu, dy = v.y - mu, dz = v.z - mu, dw = v.w - mu;
      float s2 = (dx * dx + dy * dy) + (dz * dz + dw * dw);
      #pragma unroll
      for (int m = 1; m < 32; m <<= 1) s2 += __shfl_xor(s2, m);
      float rstd = rsqrtf(s2 * (1.f / 128.f) + 1e-5f);
      u32 p0 = cvtpk(dx * rstd * gg.x + bb.x, dy * rstd * gg.y + bb.y);
      u32 p1 = cvtpk(dz * rstd * gg.z + bb.z, dw * rstd * gg.w + bb.w);
      *(uint2*)&As[r][l32 * 4] = make_uint2(p0, p1);
    }
  }

  fv4 acc[MI][NF];
  #pragma unroll
  for (int i = 0; i < MI; i++)
    #pragma unroll
    for (int j = 0; j < NF; j++) acc[i][j] = (fv4){0.f, 0.f, 0.f, 0.f};

  for (int k0 = 0; k0 < 128; k0 += BK) {
    #pragma unroll
    for (int p = 0; p < BN / 64; p++) {
      int ch = tid + p * 256;
      int row = ch >> 2, c8 = (ch & 3) * 8;
      int n = n0 + row;
      uint4 v = make_uint4(0u, 0u, 0u, 0u);
      if (n < N) v = *(const uint4*)(Btp + (size_t)n * 128 + k0 + c8);
      *(uint4*)&Bs[row][c8] = v;
    }
    __syncthreads();
    bfv8 a[MI], b[NF];
    #pragma unroll
    for (int i = 0; i < MI; i++)
      a[i] = *(const bfv8*)&As[wm * (BM / 2) + i * 16 + fr][k0 + fk];
    #pragma unroll
    for (int j = 0; j < NF; j++)
      b[j] = *(const bfv8*)&Bs[wn * (BN / 2) + j * 16 + fr][fk];
    #pragma unroll
    for (int i = 0; i < MI; i++)
      #pragma unroll
      for (int j = 0; j < NF; j++)
        acc[i][j] = __builtin_amdgcn_mfma_f32_16x16x32_bf16(a[i], b[j], acc[i][j], 0, 0, 0);
    __syncthreads();
  }

  const int row0 = m0 + wm * (BM / 2);
  const int col0 = n0 + wn * (BN / 2);
  const int lr   = (lane >> 4) * 4;
  #pragma unroll
  for (int j = 0; j < NF; j++) {
    int col = col0 + j * 16 + fr;
    if (col >= N) continue;
    float bz = BIAS ? bias[col] : 0.f;
    #pragma unroll
    for (int i = 0; i < MI; i++) {
      #pragma unroll
      for (int q = 0; q < 4; q++) {
        int row = row0 + i * 16 + lr + q;
        float v = acc[i][j][q] + bz;
        if (RELU) v = fmaxf(v, 0.f);
        if (OMODE == 0) ((u16*)Cout)[(size_t)row * N + col] = f2b(v);
        else            ((float*)Cout)[(size_t)row * N + col] = v;
      }
    }
  }
}

// ------------------------------------------------------- MFMA attention ----
// one block per (b, h, qhalf); 4 waves; wave q-tiles {w, 7-w} of its half.
// Online softmax (flash): rolled loop over key tiles, no score arrays.
// 16x16x16 MFMA: S^T = mfma(K,Q) leaves lane (fr,g) holding P rows 4g..4g+3
// of col q=fr == exactly the PV B-fragment. Zero cross-lane data movement.
__global__ __launch_bounds__(256) void attn_mfma(
    const u16* __restrict__ qkv, u16* __restrict__ out) {
  const float scale = 0.08838834764831843f;   // C^-0.5 (C=128, per reference!)
  __shared__ u16 Qs[128][20];
  __shared__ u16 Ks[TSEQ][20];
  __shared__ u16 Vt[HD][284];                 // 568B rows: 8B-aligned, ~2-way banks
  const int blk = blockIdx.x;
  const int qh = blk & 1;
  const int h  = (blk >> 1) & (NH - 1);
  const int b  = blk >> 4;
  const int tid = threadIdx.x;

  #pragma unroll
  for (int p = 0; p < 2; p++) {
    int idx = tid + p * 256;
    int r  = idx >> 1;
    int c8 = (idx & 1) * 8;
    const u16* base = qkv + (size_t)(b * TSEQ + r) * 384 + h * HD + c8;
    uint4 k  = *(const uint4*)(base + CDIM);
    u16v8 v  = *(const u16v8*)(base + 2 * CDIM);
    *(uint4*)&Ks[r][c8] = k;
    #pragma unroll
    for (int i = 0; i < 8; i++) Vt[c8 + i][r] = v[i];
  }
  {
    int r  = tid >> 1;
    int c8 = (tid & 1) * 8;
    const u16* base = qkv + (size_t)(b * TSEQ + qh * 128 + r) * 384 + h * HD + c8;
    *(uint4*)&Qs[r][c8] = *(const uint4*)(base);
  }
  __syncthreads();

  const int wv   = tid >> 6;
  const int lane = tid & 63;
  const int fr = lane & 15;
  const int g  = lane >> 4;

  #pragma unroll 1
  for (int qi = 0; qi < 2; qi++) {
    const int qt = qh * 8 + (qi ? (7 - wv) : wv);     // wave-uniform
    s4 qf = *(const s4*)&Qs[(qt & 7) * 16 + fr][g * 4];

    float m = -3.4e38f, l = 0.f;
    fv4 accO = (fv4){0.f, 0.f, 0.f, 0.f};

    for (int st = 0; st < qt; st++) {                 // full (unmasked) tiles
      s4 kf = *(const s4*)&Ks[st * 16 + fr][g * 4];
      fv4 sc = mfma16(kf, qf, (fv4){0.f, 0.f, 0.f, 0.f});
      float s0 = sc[0] * scale, s1 = sc[1] * scale;
      float s2 = sc[2] * scale, s3 = sc[3] * scale;
      float tm = fmaxf(fmaxf(s0, s1), fmaxf(s2, s3));
      tm = fmaxf(tm, __shfl_xor(tm, 16));
      tm = fmaxf(tm, __shfl_xor(tm, 32));
      float mn = fmaxf(m, tm);
      float corr = __expf(m - mn);                    // 1 if max unchanged
      float e0 = __expf(s0 - mn), e1 = __expf(s1 - mn);
      float e2 = __expf(s2 - mn), e3 = __expf(s3 - mn);
      l = l * corr + (e0 + e1) + (e2 + e3);
      accO[0] *= corr; accO[1] *= corr; accO[2] *= corr; accO[3] *= corr;
      s4 pf = __builtin_bit_cast(s4, make_uint2(cvtpk(e0, e1), cvtpk(e2, e3)));
      s4 vf = *(const s4*)&Vt[fr][st * 16 + g * 4];
      accO = mfma16(vf, pf, accO);
      m = mn;
    }
    {                                                  // diagonal tile st==qt
      s4 kf = *(const s4*)&Ks[qt * 16 + fr][g * 4];
      fv4 sc = mfma16(kf, qf, (fv4){0.f, 0.f, 0.f, 0.f});
      const float NEG = -3.4e38f;
      float s0 = (4 * g + 0 > fr) ? NEG : sc[0] * scale;
      float s1 = (4 * g + 1 > fr) ? NEG : sc[1] * scale;
      float s2 = (4 * g + 2 > fr) ? NEG : sc[2] * scale;
      float s3 = (4 * g + 3 > fr) ? NEG : sc[3] * scale;
      float tm = fmaxf(fmaxf(s0, s1), fmaxf(s2, s3));
      tm = fmaxf(tm, __shfl_xor(tm, 16));
      tm = fmaxf(tm, __shfl_xor(tm, 32));
      float mn = fmaxf(m, tm);
      float corr = __expf(m - mn);
      float e0 = (s0 <= -1e37f) ? 0.f : __expf(s0 - mn);
      float e1 = (s1 <= -1e37f) ? 0.f : __expf(s1 - mn);
      float e2 = (s2 <= -1e37f) ? 0.f : __expf(s2 - mn);
      float e3 = (s3 <= -1e37f) ? 0.f : __expf(s3 - mn);
      l = l * corr + (e0 + e1) + (e2 + e3);
      accO[0] *= corr; accO[1] *= corr; accO[2] *= corr; accO[3] *= corr;
      s4 pf = __builtin_bit_cast(s4, make_uint2(cvtpk(e0, e1), cvtpk(e2, e3)));
      s4 vf = *(const s4*)&Vt[fr][qt * 16 + g * 4];
      accO = mfma16(vf, pf, accO);
    }

    float lt = l;
    lt += __shfl_xor(lt, 16);
    lt += __shfl_xor(lt, 32);
    const float inv = 1.f / lt;

    const int q_glob = qt * 16 + fr;
    u32 lo = cvtpk(accO[0] * inv, accO[1] * inv);
    u32 hi = cvtpk(accO[2] * inv, accO[3] * inv);
    *(uint2*)(out + (size_t)(b * TSEQ + q_glob) * CDIM + h * HD + 4 * g) =
        make_uint2(lo, hi);
  }
}

// ----------------------------------------------------------------- host ----
extern "C" void kernel_launch(void* const* d_in, const int* in_sizes, int n_in,
                              void* d_out, int out_size, void* d_ws, size_t ws_size,
                              hipStream_t stream) {
  const int*   tokens  = (const int*)  d_in[0];
  const float* tok_emb = (const float*)d_in[1];
  const float* pos_emb = (const float*)d_in[2];
  const float* Wq      = (const float*)d_in[3];
  const float* Wk      = (const float*)d_in[4];
  const float* Wv      = (const float*)d_in[5];
  const float* Wproj   = (const float*)d_in[6];
  const float* bproj   = (const float*)d_in[7];
  const float* ln1_g   = (const float*)d_in[8];
  const float* ln1_b   = (const float*)d_in[9];
  const float* ln2_g   = (const float*)d_in[10];
  const float* ln2_b   = (const float*)d_in[11];
  const float* W1      = (const float*)d_in[12];
  const float* b1      = (const float*)d_in[13];
  const float* W2      = (const float*)d_in[14];
  const float* b2      = (const float*)d_in[15];
  const float* lnf_g   = (const float*)d_in[16];
  const float* lnf_b   = (const float*)d_in[17];
  const float* Wlm     = (const float*)d_in[18];
  const float* blm     = (const float*)d_in[19];
  float* out = (float*)d_out;

  char* W = (char*)d_ws;
  float* x    = (float*)(W);                   // 16384*128 f32      (8 MB)
  u16*   qkvb = (u16*)  (W + 12582912);        // 16384*384 bf16     (12 MB)
  u16*   att  = (u16*)  (W + 25165824);        // 16384*128 bf16     (4 MB)
  u16*   hbuf = (u16*)  (W + 29360128);        // 16384*512 bf16     (16 MB)
  u16*   wqkv = (u16*)  (W + 46137344);        // 6*384*128
  u16*   wpj  = (u16*)  (W + 46727168);        // 6*128*128
  u16*   w1t  = (u16*)  (W + 46923776);        // 6*512*128
  u16*   w2t  = (u16*)  (W + 47710208);        // 6*128*512
  u16*   wlmt = (u16*)  (W + 48496640);        // 3149*128

  packqkv_bf16<<<(NL * 384 * CDIM + 255) / 256, 256, 0, stream>>>(Wq, Wk, Wv, wqkv);
  transpose_cast_t<<<dim3(4, 4, NL), 256, 0, stream>>>(Wproj, wpj, CDIM, CDIM);
  transpose_cast_t<<<dim3(16, 4, NL), 256, 0, stream>>>(W1, w1t, CDIM, FFD);
  transpose_cast_t<<<dim3(4, 16, NL), 256, 0, stream>>>(W2, w2t, FFD, CDIM);
  transpose_cast_t<<<dim3((NV + 31) / 32, 4, 1), 256, 0, stream>>>(Wlm, wlmt, CDIM, NV);
  embed_kernel<<<(BT * CDIM / 4 + 255) / 256, 256, 0, stream>>>(tokens, tok_emb, pos_emb, x);

  for (int l = 0; l < NL; l++) {
    gemm_ln_mfma<0, false, false, 64, 128><<<dim3(3, BT / 64), 256, 0, stream>>>(
        x, wqkv + (size_t)l * 384 * CDIM, ln1_g + l * CDIM, ln1_b + l * CDIM,
        nullptr, qkvb, BT, 384);
    attn_mfma<<<NBAT * NH * 2, 256, 0, stream>>>(qkvb, att);
    gemm_mfma<2, true, false, 64, 64><<<dim3(2, BT / 64), 256, 0, stream>>>(
        att, wpj + (size_t)l * CDIM * CDIM, bproj + l * CDIM, x, BT, CDIM, CDIM);
    gemm_ln_mfma<0, true, true, 64, 128><<<dim3(4, BT / 64), 256, 0, stream>>>(
        x, w1t + (size_t)l * FFD * CDIM, ln2_g + l * CDIM, ln2_b + l * CDIM,
        b1 + l * FFD, hbuf, BT, FFD);
    gemm_mfma<2, true, false, 64, 64><<<dim3(2, BT / 64), 256, 0, stream>>>(
        hbuf, w2t + (size_t)l * CDIM * FFD, b2 + l * CDIM, x, BT, CDIM, FFD);
  }
  gemm_ln_mfma<1, true, false, 128, 128><<<dim3((NV + 127) / 128, BT / 128), 256, 0, stream>>>(
      x, wlmt, lnf_g, lnf_b, blm, out, BT, NV);
}